// Round 12
// baseline (891.971 us; speedup 1.0000x reference)
//
#include <hip/hip_runtime.h>
#include <math.h>

typedef __attribute__((ext_vector_type(8))) short bf16x8;
typedef __attribute__((ext_vector_type(4))) float f32x4;
typedef __attribute__((ext_vector_type(2))) float f32x2;
typedef __attribute__((ext_vector_type(4))) unsigned short u16x4;
typedef __attribute__((ext_vector_type(2))) _Float16 f16x2;

static __device__ __forceinline__ short f2bf(float f) {
  unsigned u = __builtin_bit_cast(unsigned, f);
  u += 0x7fffu + ((u >> 16) & 1u);
  return (short)(u >> 16);
}
static __device__ __forceinline__ float bf2f(unsigned short s) {
  unsigned u = ((unsigned)s) << 16;
  return __builtin_bit_cast(float, u);
}
static __device__ __forceinline__ f32x4 mfma16(bf16x8 a, bf16x8 b, f32x4 c) {
  return __builtin_amdgcn_mfma_f32_16x16x32_bf16(a, b, c, 0, 0, 0);
}
static __device__ __forceinline__ bf16x8 pack8v(f32x4 a, f32x4 b) {
  bf16x8 r;
  r[0]=f2bf(a[0]); r[1]=f2bf(a[1]); r[2]=f2bf(a[2]); r[3]=f2bf(a[3]);
  r[4]=f2bf(b[0]); r[5]=f2bf(b[1]); r[6]=f2bf(b[2]); r[7]=f2bf(b[3]);
  return r;
}
static __device__ __forceinline__ float fastrcp(float x) {
  float r;
  asm("v_rcp_f32_e32 %0, %1" : "=v"(r) : "v"(x));
  return r;
}
static __device__ __forceinline__ float dot4(f32x4 a, f32x4 b) {
  return a[0]*b[0] + a[1]*b[1] + a[2]*b[2] + a[3]*b[3];
}

#define LGKM_BARRIER() do {                                   \
    asm volatile("s_waitcnt lgkmcnt(0)" ::: "memory");        \
    __builtin_amdgcn_s_barrier();                             \
    __builtin_amdgcn_sched_barrier(0);                        \
  } while (0)

// ---------------- gi = x @ Wih^T, compact 4-row quad tiles (700 blocks x 16 tiles) ----------------
__global__ __launch_bounds__(512) void gi_gemm_kernel(
    const int* __restrict__ seq0, const int* __restrict__ seq1,
    const int* __restrict__ seq2, const int* __restrict__ seq3,
    const float* __restrict__ item_emb, const float* __restrict__ Wih,
    unsigned short* __restrict__ gi_t50, unsigned short* __restrict__ gi_click)
{
  const int b = blockIdx.x;
  int beh, tile0;
  if (b < 100)      { beh = 0; tile0 = b * 16; }
  else if (b < 200) { beh = 1; tile0 = (b - 100) * 16; }
  else if (b < 300) { beh = 2; tile0 = (b - 200) * 16; }
  else              { beh = 3; tile0 = (b - 300) * 16; }
  const int T = (beh == 3) ? 200 : 50;
  const int* seq = (beh == 0) ? seq0 : (beh == 1) ? seq1 : (beh == 2) ? seq2 : seq3;
  unsigned short* gibase = (beh == 3) ? gi_click : (gi_t50 + (size_t)beh * 9830400);

  const int tid = threadIdx.x;
  const int wave = tid >> 6, lane = tid & 63, lrow = lane & 15, lk8 = lane >> 4;
  const int bcol = wave * 16 + lrow;

  bf16x8 wif[3][4];
  const float* WihB = Wih + (size_t)beh * 384 * 128;
#pragma unroll
  for (int g = 0; g < 3; ++g) {
    const int wr = g * 128 + bcol;
#pragma unroll
    for (int kt = 0; kt < 4; ++kt) {
      const int k0 = kt * 32 + lk8 * 8;
      f32x4 a0 = *(const f32x4*)(WihB + (size_t)wr * 128 + k0);
      f32x4 a1 = *(const f32x4*)(WihB + (size_t)wr * 128 + k0 + 4);
      wif[g][kt] = pack8v(a0, a1);
    }
  }

  __shared__ short xt[16][132];
  const int gj = tid >> 5;
  const int gc = (tid & 31) * 4;

  for (int ti = 0; ti < 16; ++ti) {
    const int tile = tile0 + ti;
    const int r0blk = tile / T;
    const int t = tile - r0blk * T;
    {
      const int sidx = seq[(size_t)(r0blk * 16 + gj) * T + t];
      const f32x4 xv = *(const f32x4*)(item_emb + (size_t)sidx * 128 + gc);
      xt[gj][gc]     = f2bf(xv[0]);
      xt[gj][gc + 1] = f2bf(xv[1]);
      xt[gj][gc + 2] = f2bf(xv[2]);
      xt[gj][gc + 3] = f2bf(xv[3]);
    }
    __syncthreads();
    bf16x8 ax[4];
#pragma unroll
    for (int kt = 0; kt < 4; ++kt)
      ax[kt] = *(const bf16x8*)&xt[lrow][kt * 32 + lk8 * 8];
    f32x4 acc[3] = {{0,0,0,0},{0,0,0,0},{0,0,0,0}};
#pragma unroll
    for (int kt = 0; kt < 4; ++kt) {
      acc[0] = mfma16(ax[kt], wif[0][kt], acc[0]);
      acc[1] = mfma16(ax[kt], wif[1][kt], acc[1]);
      acc[2] = mfma16(ax[kt], wif[2][kt], acc[2]);
    }
    unsigned short* base = gibase + ((size_t)(r0blk * 4 + lk8) * T + t) * 1536;
    unsigned short* dst = base + bcol * 4;
#pragma unroll
    for (int g = 0; g < 3; ++g) {
      u16x4 o;
      o[0] = (unsigned short)f2bf(acc[g][0]);
      o[1] = (unsigned short)f2bf(acc[g][1]);
      o[2] = (unsigned short)f2bf(acc[g][2]);
      o[3] = (unsigned short)f2bf(acc[g][3]);
      *(u16x4*)(dst + g * 512) = o;
    }
    __syncthreads();
  }
}

// ---------------- GRU recurrence: 1 row/block. blocks 0..511 click, 512..2047 t50, 2048..2175 Ebf workers ----------------
__global__ __launch_bounds__(256, 2) void gru_rec6_kernel(
    const float* __restrict__ Whh, const float* __restrict__ bih,
    const float* __restrict__ bhh,
    const unsigned short* __restrict__ gi_t50,
    const unsigned short* __restrict__ gi_click,
    const float* __restrict__ item_emb, unsigned short* __restrict__ Ebf,
    float* __restrict__ e_out)
{
  __shared__ short h0[16][140];
  __shared__ short h1[16][140];
  const int tid = threadIdx.x;

  if (blockIdx.x >= 2048) {
    // workers: cast item_emb -> Ebf bf16 row-major [50048][128], pad rows zeroed
    const int wb = blockIdx.x - 2048;
    for (size_t i8 = (size_t)(wb * 256 + tid) * 8; i8 < 50048u * 128u; i8 += 32768u * 8u) {
      const int row = (int)(i8 >> 7);
      bf16x8 o = {0,0,0,0,0,0,0,0};
      if (row < 50001) {
        const f32x4 a = *(const f32x4*)(item_emb + i8);
        const f32x4 b = *(const f32x4*)(item_emb + i8 + 4);
        o = pack8v(a, b);
      }
      *(bf16x8*)(Ebf + i8) = o;
    }
    return;
  }

  int beh, row;
  if (blockIdx.x < 512) { beh = 3; row = blockIdx.x; }
  else { beh = (blockIdx.x - 512) >> 9; row = (blockIdx.x - 512) & 511; }
  const int T = (beh == 3) ? 200 : 50;
  const int quad = row >> 2, rq = row & 3;
  const unsigned short* gib =
      ((beh == 3) ? gi_click : (gi_t50 + (size_t)beh * 9830400)) + (size_t)quad * T * 1536;

  const int w = tid >> 6;
  const int lane = tid & 63;
  const int lrow = lane & 15;
  const int lk8 = lane >> 4;
  const int col0 = w * 32 + lrow;
  const int col1 = col0 + 16;

  bf16x8 whf[3][2][4];
  const float* WhhB = Whh + (size_t)beh * 384 * 128;
#pragma unroll
  for (int g = 0; g < 3; ++g) {
#pragma unroll
    for (int ct = 0; ct < 2; ++ct) {
      const int wr = g * 128 + (ct ? col1 : col0);
#pragma unroll
      for (int kt = 0; kt < 4; ++kt) {
        const int k0 = kt * 32 + lk8 * 8;
        f32x4 b0 = *(const f32x4*)(WhhB + (size_t)wr * 128 + k0);
        f32x4 b1 = *(const f32x4*)(WhhB + (size_t)wr * 128 + k0 + 4);
        whf[g][ct][kt] = pack8v(b0, b1);
      }
    }
  }
  float bR[2], bZ[2], bN[2], bHN[2];
#pragma unroll
  for (int ct = 0; ct < 2; ++ct) {
    const int c = ct ? col1 : col0;
    bR[ct]  = bih[beh * 384 + c] + bhh[beh * 384 + c];
    bZ[ct]  = bih[beh * 384 + 128 + c] + bhh[beh * 384 + 128 + c];
    bN[ct]  = bih[beh * 384 + 256 + c];
    bHN[ct] = bhh[beh * 384 + 256 + c];
  }

  for (int i = tid; i < 16 * 140; i += 256) { ((short*)h0)[i] = 0; ((short*)h1)[i] = 0; }
  float hreg[2] = {0.f, 0.f};
  __syncthreads();

  // the block's single row lives in gi quad element rq; only lk8==0 lanes consume
  const unsigned short* gp0 = gib + col0 * 4 + rq;
  const unsigned short* gp1 = gib + col1 * 4 + rq;

  unsigned short ga[10], gb[10];   // 5 steps x 2ct (3 gates packed: s*2+ct indexes triple base)

  // layout: BUF[s*2+ct] unused; store per (s, ct, g) in 30... keep 30 regs but only lk8==0 lanes load
  unsigned short gA[30], gB[30];

#define LOAD_CHUNK(BUF, C0) do {                                              \
    if (lk8 == 0) {                                                           \
      _Pragma("unroll")                                                       \
      for (int _s = 0; _s < 5; ++_s) {                                        \
        const size_t _o = (size_t)((C0) + _s) * 1536;                         \
        _Pragma("unroll")                                                     \
        for (int _g = 0; _g < 3; ++_g) {                                      \
          BUF[_s * 6 + 0 * 3 + _g] = gp0[_o + _g * 512];                      \
          BUF[_s * 6 + 1 * 3 + _g] = gp1[_o + _g * 512];                      \
        }                                                                     \
      }                                                                       \
    }                                                                         \
  } while (0)

  short (*hin)[140] = h0;
  short (*hout)[140] = h1;

#define STEP(BUF, S) do {                                                     \
    bf16x8 ah[4];                                                             \
    _Pragma("unroll")                                                         \
    for (int kt = 0; kt < 4; ++kt)                                            \
      ah[kt] = *(const bf16x8*)&hin[lrow][kt * 32 + lk8 * 8];                 \
    f32x4 hr_[2], hz_[2], hn_[2];                                             \
    _Pragma("unroll")                                                         \
    for (int ct = 0; ct < 2; ++ct) {                                          \
      hr_[ct] = (f32x4){0,0,0,0}; hz_[ct] = (f32x4){0,0,0,0}; hn_[ct] = (f32x4){0,0,0,0}; \
      _Pragma("unroll")                                                       \
      for (int kt = 0; kt < 4; ++kt) {                                        \
        hr_[ct] = mfma16(ah[kt], whf[0][ct][kt], hr_[ct]);                    \
        hz_[ct] = mfma16(ah[kt], whf[1][ct][kt], hz_[ct]);                    \
        hn_[ct] = mfma16(ah[kt], whf[2][ct][kt], hn_[ct]);                    \
      }                                                                       \
    }                                                                         \
    if (lk8 == 0) {                                                           \
      _Pragma("unroll")                                                       \
      for (int ct = 0; ct < 2; ++ct) {                                        \
        const float xr = bf2f(BUF[(S)*6 + ct*3 + 0]) + bR[ct] + hr_[ct][0];   \
        const float xz = bf2f(BUF[(S)*6 + ct*3 + 1]) + bZ[ct] + hz_[ct][0];   \
        const float ea = __expf(-xr);                                         \
        const float eb = __expf(-xz);                                         \
        const float pa = 1.f + ea, pb = 1.f + eb;                             \
        const float rd = fastrcp(pa * pb);                                    \
        const float rr = pb * rd;                                             \
        const float zz = pa * rd;                                             \
        const float tn = bf2f(BUF[(S)*6 + ct*3 + 2]) + bN[ct] + rr * (hn_[ct][0] + bHN[ct]); \
        const float tt = __expf(-2.f * tn);                                   \
        const float nn = (1.f - tt) * fastrcp(1.f + tt);                      \
        hreg[ct] = nn + zz * (hreg[ct] - nn);                                 \
        hout[0][ct ? col1 : col0] = f2bf(hreg[ct]);                           \
      }                                                                       \
    }                                                                         \
    LGKM_BARRIER();                                                           \
    short (*_tmp)[140] = hin; hin = hout; hout = _tmp;                        \
  } while (0)

  LOAD_CHUNK(gA, 0);
  for (int c = 0; c < T; c += 10) {
    if (c + 5 < T) LOAD_CHUNK(gB, c + 5);
    STEP(gA, 0); STEP(gA, 1); STEP(gA, 2); STEP(gA, 3); STEP(gA, 4);
    if (c + 10 < T) LOAD_CHUNK(gA, c + 10);
    STEP(gB, 0); STEP(gB, 1); STEP(gB, 2); STEP(gB, 3); STEP(gB, 4);
  }
#undef STEP
#undef LOAD_CHUNK

  if (lk8 == 0) {
#pragma unroll
    for (int ct = 0; ct < 2; ++ct)
      e_out[(size_t)row * 512 + (ct ? col1 : col0) * 4 + beh] = hreg[ct];
  }
}

// ---------------- route: fused b-update + softmax(c) + v + vn (b in fp16) ----------------
template<int MODE>
__global__ __launch_bounds__(256, 1) void route_kernel(
    const _Float16* __restrict__ b_old, _Float16* __restrict__ b_new,
    const float* __restrict__ e_buf, const float* __restrict__ W,
    const float* __restrict__ coef_buf,
    const float* __restrict__ w_scale, const float* __restrict__ bias_vec,
    const float* __restrict__ alpha,
    float* __restrict__ v_buf, float* __restrict__ vn_buf)
{
  __shared__ float e_lds[4][128][4];
  __shared__ float vacc[4][4][128][8];
  const int g0 = blockIdx.x * 4;
  const int tid = threadIdx.x;
  const int wv = tid >> 6, ln = tid & 63;
  const int c0 = ln * 2;
  for (int i = tid; i < 2048; i += 256) ((float*)e_lds)[i] = e_buf[(size_t)g0 * 512 + i];

  f32x4 cf[4][2][2];
  if (MODE != 0) {
#pragma unroll
    for (int g = 0; g < 4; ++g)
#pragma unroll
      for (int cc = 0; cc < 2; ++cc) {
        cf[g][cc][0] = *(const f32x4*)(coef_buf + (size_t)(g0 + g) * 1024 + (c0 + cc) * 8);
        cf[g][cc][1] = *(const f32x4*)(coef_buf + (size_t)(g0 + g) * 1024 + (c0 + cc) * 8 + 4);
      }
  }
  __syncthreads();

  f32x4 av[4][2][2];
#pragma unroll
  for (int g = 0; g < 4; ++g)
#pragma unroll
    for (int cc = 0; cc < 2; ++cc) { av[g][cc][0] = (f32x4){0,0,0,0}; av[g][cc][1] = (f32x4){0,0,0,0}; }

  const int hbeg = wv * 32;
  for (int h = hbeg; h < hbeg + 32; ++h) {
    f32x4 wr[4][2][2];
#pragma unroll
    for (int t = 0; t < 4; ++t) {
      const float* wp = W + ((size_t)(h * 4 + t) * 128 + c0) * 8;
      wr[t][0][0] = *(const f32x4*)(wp);
      wr[t][0][1] = *(const f32x4*)(wp + 4);
      wr[t][1][0] = *(const f32x4*)(wp + 8);
      wr[t][1][1] = *(const f32x4*)(wp + 12);
    }
    f16x2 bo[4];
    if (MODE == 2) {
#pragma unroll
      for (int g = 0; g < 4; ++g)
        bo[g] = *(const f16x2*)(b_old + (size_t)(g0 + g) * 16384 + h * 128 + c0);
    }
#pragma unroll
    for (int g = 0; g < 4; ++g) {
      const f32x4 ev = *(const f32x4*)&e_lds[g][h][0];
      f32x4 u[2][2];
#pragma unroll
      for (int cc = 0; cc < 2; ++cc)
#pragma unroll
        for (int dd = 0; dd < 2; ++dd)
          u[cc][dd] = ev[0]*wr[0][cc][dd] + ev[1]*wr[1][cc][dd]
                    + ev[2]*wr[2][cc][dd] + ev[3]*wr[3][cc][dd];
      float cv0, cv1;
      if (MODE == 0) {
        cv0 = 0.0078125f; cv1 = 0.0078125f;
      } else {
        float b0 = dot4(u[0][0], cf[g][0][0]) + dot4(u[0][1], cf[g][0][1]);
        float b1 = dot4(u[1][0], cf[g][1][0]) + dot4(u[1][1], cf[g][1][1]);
        if (MODE == 2) { b0 += (float)bo[g][0]; b1 += (float)bo[g][1]; }
        if (MODE == 1) {
          f16x2 bw; bw[0] = (_Float16)b0; bw[1] = (_Float16)b1;
          *(f16x2*)(b_new + (size_t)(g0 + g) * 16384 + h * 128 + c0) = bw;
        }
        float m = fmaxf(b0, b1);
#pragma unroll
        for (int off = 32; off > 0; off >>= 1) m = fmaxf(m, __shfl_xor(m, off));
        const float e0 = __expf(b0 - m), e1 = __expf(b1 - m);
        float s = e0 + e1;
#pragma unroll
        for (int off = 32; off > 0; off >>= 1) s += __shfl_xor(s, off);
        const float inv = 1.f / s;
        cv0 = e0 * inv; cv1 = e1 * inv;
      }
      av[g][0][0] += cv0 * u[0][0]; av[g][0][1] += cv0 * u[0][1];
      av[g][1][0] += cv1 * u[1][0]; av[g][1][1] += cv1 * u[1][1];
    }
  }
#pragma unroll
  for (int g = 0; g < 4; ++g)
#pragma unroll
    for (int cc = 0; cc < 2; ++cc) {
      *(f32x4*)&vacc[wv][g][c0 + cc][0] = av[g][cc][0];
      *(f32x4*)&vacc[wv][g][c0 + cc][4] = av[g][cc][1];
    }
  __syncthreads();

  const float al = alpha[0];
  const int rg = tid >> 6;
  const int rc = (tid & 63) * 2;
#pragma unroll
  for (int cc = 0; cc < 2; ++cc) {
    const int c = rc + cc;
    f32x4 s0 = *(const f32x4*)&vacc[0][rg][c][0];
    f32x4 s1 = *(const f32x4*)&vacc[0][rg][c][4];
#pragma unroll
    for (int wq = 1; wq < 4; ++wq) {
      s0 += *(const f32x4*)&vacc[wq][rg][c][0];
      s1 += *(const f32x4*)&vacc[wq][rg][c][4];
    }
    s0 *= al; s1 *= al;
    *(f32x4*)(v_buf + (size_t)(g0 + rg) * 1024 + c * 8) = s0;
    *(f32x4*)(v_buf + (size_t)(g0 + rg) * 1024 + c * 8 + 4) = s1;
    const float ss = dot4(s0, s0) + dot4(s1, s1);
    vn_buf[(g0 + rg) * 128 + c] = sqrtf(ss) * w_scale[c] + bias_vec[c];
  }
}

// ---------------- flash: p-partials = softmax-stream(vn @ Ebf^T) @ Ebf ----------------
__global__ __launch_bounds__(256, 2) void flash_kernel(
    const float* __restrict__ vn, const unsigned short* __restrict__ Ebf,
    float* __restrict__ o_part, float* __restrict__ ms_part)
{
  __shared__ short e_nat[64][136];
  __shared__ short e_tr[128][72];
  __shared__ short p_lds[4][16][72];
  const int xc = blockIdx.x;
  const int tid = threadIdx.x;
  const int w = tid >> 6, lane = tid & 63, lrow = lane & 15, lk8 = lane >> 4;
  const int rowbase = blockIdx.y * 64 + w * 16;

  bf16x8 qf[4];
#pragma unroll
  for (int kt = 0; kt < 4; ++kt) {
    const float* p = vn + (size_t)(rowbase + lrow) * 128 + kt * 32 + lk8 * 8;
    qf[kt] = pack8v(*(const f32x4*)p, *(const f32x4*)(p + 4));
  }

  f32x4 o_acc[8] = {{0,0,0,0},{0,0,0,0},{0,0,0,0},{0,0,0,0},
                    {0,0,0,0},{0,0,0,0},{0,0,0,0},{0,0,0,0}};
  float m_run[4] = {-1e30f, -1e30f, -1e30f, -1e30f};
  float s_run[4] = {0.f, 0.f, 0.f, 0.f};

  const int kbeg = xc * 1024;
  const int nst = (kbeg + 1024 <= 50048) ? 16 : (50048 - kbeg) / 64;
  const int sr = tid >> 2, sseg = (tid & 3) * 32;

  for (int st = 0; st < nst; ++st) {
    const int v0 = kbeg + st * 64;
    {
      bf16x8 ev[4];
#pragma unroll
      for (int q = 0; q < 4; ++q)
        ev[q] = *(const bf16x8*)(Ebf + (size_t)(v0 + sr) * 128 + sseg + q * 8);
#pragma unroll
      for (int q = 0; q < 4; ++q)
        *(bf16x8*)&e_nat[sr][sseg + q * 8] = ev[q];
#pragma unroll
      for (int q = 0; q < 4; ++q)
#pragma unroll
        for (int j = 0; j < 8; ++j)
          e_tr[sseg + q * 8 + j][sr] = ev[q][j];
    }
    __syncthreads();
    f32x4 sacc[4] = {{0,0,0,0},{0,0,0,0},{0,0,0,0},{0,0,0,0}};
#pragma unroll
    for (int kt = 0; kt < 4; ++kt) {
#pragma unroll
      for (int nt = 0; nt < 4; ++nt) {
        const bf16x8 bfr = *(const bf16x8*)&e_nat[nt * 16 + lrow][kt * 32 + lk8 * 8];
        sacc[nt] = mfma16(qf[kt], bfr, sacc[nt]);
      }
    }
    if (v0 + 64 > 50001) {
#pragma unroll
      for (int nt = 0; nt < 4; ++nt)
        if (v0 + nt * 16 + lrow >= 50001)
          sacc[nt] = (f32x4){-1e30f, -1e30f, -1e30f, -1e30f};
    }
#pragma unroll
    for (int e2 = 0; e2 < 4; ++e2) {
      float mt = fmaxf(fmaxf(sacc[0][e2], sacc[1][e2]), fmaxf(sacc[2][e2], sacc[3][e2]));
      mt = fmaxf(mt, __shfl_xor(mt, 1));
      mt = fmaxf(mt, __shfl_xor(mt, 2));
      mt = fmaxf(mt, __shfl_xor(mt, 4));
      mt = fmaxf(mt, __shfl_xor(mt, 8));
      const float mn = fmaxf(m_run[e2], mt);
      const float scale = __expf(m_run[e2] - mn);
      m_run[e2] = mn;
      float pv[4];
#pragma unroll
      for (int nt = 0; nt < 4; ++nt) pv[nt] = __expf(sacc[nt][e2] - mn);
      float ps = pv[0] + pv[1] + pv[2] + pv[3];
      ps += __shfl_xor(ps, 1);
      ps += __shfl_xor(ps, 2);
      ps += __shfl_xor(ps, 4);
      ps += __shfl_xor(ps, 8);
      s_run[e2] = s_run[e2] * scale + ps;
#pragma unroll
      for (int nt8 = 0; nt8 < 8; ++nt8) o_acc[nt8][e2] *= scale;
#pragma unroll
      for (int nt = 0; nt < 4; ++nt)
        p_lds[w][lk8 * 4 + e2][nt * 16 + lrow] = f2bf(pv[nt]);
    }
#pragma unroll
    for (int kt2 = 0; kt2 < 2; ++kt2) {
      const bf16x8 pa = *(const bf16x8*)&p_lds[w][lrow][kt2 * 32 + lk8 * 8];
#pragma unroll
      for (int nt8 = 0; nt8 < 8; ++nt8) {
        const bf16x8 bfr = *(const bf16x8*)&e_tr[nt8 * 16 + lrow][kt2 * 32 + lk8 * 8];
        o_acc[nt8] = mfma16(pa, bfr, o_acc[nt8]);
      }
    }
    __syncthreads();
  }

#pragma unroll
  for (int nt8 = 0; nt8 < 8; ++nt8)
#pragma unroll
    for (int e2 = 0; e2 < 4; ++e2)
      o_part[((size_t)xc * 512 + rowbase + lk8 * 4 + e2) * 128 + nt8 * 16 + lrow] = o_acc[nt8][e2];
  if (lrow == 0) {
#pragma unroll
    for (int e2 = 0; e2 < 4; ++e2) {
      const int row = rowbase + lk8 * 4 + e2;
      ms_part[((size_t)row * 49 + xc) * 2]     = m_run[e2];
      ms_part[((size_t)row * 49 + xc) * 2 + 1] = s_run[e2];
    }
  }
}

// ---------------- combine partials -> p, then coef = concat(p, v) @ W_coef ----------------
__global__ __launch_bounds__(256) void combine_coef_kernel(
    const float* __restrict__ o_part, const float* __restrict__ ms_part,
    const float* __restrict__ v_buf, const float* __restrict__ W_coef,
    float* __restrict__ coef_buf)
{
  __shared__ float wg[4][64];
  __shared__ float p_s[4][128];
  const int g0 = blockIdx.x * 4;
  const int tid = threadIdx.x;
  const int w = tid >> 6, lane = tid & 63;
  {
    const int row = g0 + w;
    float ml = -1e30f, sl = 0.f;
    if (lane < 49) {
      ml = ms_part[((size_t)row * 49 + lane) * 2];
      sl = ms_part[((size_t)row * 49 + lane) * 2 + 1];
    }
    float M = ml;
#pragma unroll
    for (int off = 32; off > 0; off >>= 1) M = fmaxf(M, __shfl_xor(M, off));
    float e = (lane < 49) ? sl * __expf(ml - M) : 0.f;
    float S = e;
#pragma unroll
    for (int off = 32; off > 0; off >>= 1) S += __shfl_xor(S, off);
    const float inv = 1.f / S;
    if (lane < 49) wg[w][lane] = __expf(ml - M) * inv;
  }
  __syncthreads();
  {
    const int d = tid & 127, gh = tid >> 7;
    for (int gg = gh; gg < 4; gg += 2) {
      const int row = g0 + gg;
      float acc = 0.f;
      for (int x = 0; x < 49; ++x)
        acc += o_part[((size_t)x * 512 + row) * 128 + d] * wg[gg][x];
      p_s[gg][d] = acc;
    }
  }
  __syncthreads();
  const int c = tid >> 1, dh = (tid & 1) * 4;
  float vg[4][8];
#pragma unroll
  for (int g = 0; g < 4; ++g) {
    const f32x4 va = *(const f32x4*)(v_buf + (size_t)(g0 + g) * 1024 + c * 8);
    const f32x4 vb = *(const f32x4*)(v_buf + (size_t)(g0 + g) * 1024 + c * 8 + 4);
    vg[g][0]=va[0]; vg[g][1]=va[1]; vg[g][2]=va[2]; vg[g][3]=va[3];
    vg[g][4]=vb[0]; vg[g][5]=vb[1]; vg[g][6]=vb[2]; vg[g][7]=vb[3];
  }
  const float* wc = W_coef + (size_t)c * 1088 + dh;
  f32x4 acc4[4] = {{0,0,0,0},{0,0,0,0},{0,0,0,0},{0,0,0,0}};
  for (int dp = 0; dp < 128; ++dp) {
    const f32x4 w4 = *(const f32x4*)(wc + (size_t)dp * 8);
#pragma unroll
    for (int g = 0; g < 4; ++g) acc4[g] += p_s[g][dp] * w4;
  }
#pragma unroll
  for (int q = 0; q < 8; ++q) {
    const f32x4 w4 = *(const f32x4*)(wc + (size_t)(128 + q) * 8);
#pragma unroll
    for (int g = 0; g < 4; ++g) acc4[g] += vg[g][q] * w4;
  }
#pragma unroll
  for (int g = 0; g < 4; ++g)
    *(f32x4*)(coef_buf + (size_t)(g0 + g) * 1024 + c * 8 + dh) = acc4[g];
}

// ---------------- final logits fp32 into d_out (stages from fp32 item_emb) ----------------
__global__ __launch_bounds__(512) void logits32_kernel(
    const float* __restrict__ vn, const float* __restrict__ E,
    float* __restrict__ out)
{
  __shared__ short et[64][136];
  const int n0 = blockIdx.x * 64;
  const int tid = threadIdx.x;
  const int wave = tid >> 6, lane = tid & 63, lrow = lane & 15, lk8 = lane >> 4;
  {
    const int r = tid >> 3, ks = (tid & 7) * 16;
    const int v = n0 + r;
    f32x4 a = {0,0,0,0}, b = {0,0,0,0}, c = {0,0,0,0}, d = {0,0,0,0};
    if (v < 50001) {
      const float* p = E + (size_t)v * 128 + ks;
      a = *(const f32x4*)p; b = *(const f32x4*)(p + 4);
      c = *(const f32x4*)(p + 8); d = *(const f32x4*)(p + 12);
    }
    *(bf16x8*)&et[r][ks] = pack8v(a, b);
    *(bf16x8*)&et[r][ks + 8] = pack8v(c, d);
  }
  __syncthreads();
  for (int mb = 0; mb < 4; ++mb) {
    const int m0 = mb * 128;
    const int arow = m0 + wave * 16 + lrow;
    bf16x8 afr[4];
#pragma unroll
    for (int kt = 0; kt < 4; ++kt) {
      const float* p = vn + (size_t)arow * 128 + kt * 32 + lk8 * 8;
      afr[kt] = pack8v(*(const f32x4*)p, *(const f32x4*)(p + 4));
    }
    f32x4 acc[4] = {{0,0,0,0},{0,0,0,0},{0,0,0,0},{0,0,0,0}};
#pragma unroll
    for (int kt = 0; kt < 4; ++kt) {
#pragma unroll
      for (int nt = 0; nt < 4; ++nt) {
        const bf16x8 bfr = *(const bf16x8*)&et[nt * 16 + lrow][kt * 32 + lk8 * 8];
        acc[nt] = mfma16(afr[kt], bfr, acc[nt]);
      }
    }
#pragma unroll
    for (int nt = 0; nt < 4; ++nt) {
      const int col = n0 + nt * 16 + lrow;
      if (col < 50001) {
        const int row = m0 + wave * 16 + lk8 * 4;
#pragma unroll
        for (int e2 = 0; e2 < 4; ++e2)
          out[(size_t)(row + e2) * 50001 + col] = acc[nt][e2];
      }
    }
  }
}

extern "C" void kernel_launch(void* const* d_in, const int* in_sizes, int n_in,
                              void* d_out, int out_size, void* d_ws, size_t ws_size,
                              hipStream_t stream) {
  const int* seq0 = (const int*)d_in[0];
  const int* seq1 = (const int*)d_in[1];
  const int* seq2 = (const int*)d_in[2];
  const int* seq3 = (const int*)d_in[3];
  const float* item_emb = (const float*)d_in[4];
  const float* Wih = (const float*)d_in[5];
  const float* Whh = (const float*)d_in[6];
  const float* bih = (const float*)d_in[7];
  const float* bhh = (const float*)d_in[8];
  const float* W = (const float*)d_in[9];
  const float* w_scale = (const float*)d_in[10];
  const float* bias_vec = (const float*)d_in[11];
  const float* alpha = (const float*)d_in[12];
  const float* W_coef = (const float*)d_in[13];
  float* out = (float*)d_out;

  char* ws = (char*)d_ws;
  float* e_buf       = (float*)(ws);               // 1 MB
  _Float16* b_state  = (_Float16*)(ws + 1048576);  // 16.7 MB (fp16)
  float* v_buf    = (float*)(ws + 34603008);       // 2 MB
  float* vn_buf   = (float*)(ws + 36700160);       // 256 KB
  float* coef_buf = (float*)(ws + 37224448);       // 2 MB
  float* o_part   = (float*)(ws + 39325696);       // 12.85 MB
  float* ms_part  = (float*)(ws + 52170752);       // 200 KB

  unsigned short* gi_t50   = (unsigned short*)(ws + 1048576);  // 57.6 MB overlay
  unsigned short* gi_click = (unsigned short*)d_out;           // 76.8 MB in d_out
  unsigned short* Ebf = (unsigned short*)((char*)d_out + 78643200);  // 12.8 MB tail

  gi_gemm_kernel<<<dim3(700), 512, 0, stream>>>(seq0, seq1, seq2, seq3, item_emb, Wih,
                                                gi_t50, gi_click);
  gru_rec6_kernel<<<dim3(2176), 256, 0, stream>>>(Whh, bih, bhh, gi_t50, gi_click,
                                                  item_emb, Ebf, e_buf);
  // iter 0: c uniform
  route_kernel<0><<<dim3(128), 256, 0, stream>>>(nullptr, nullptr, e_buf, W, nullptr,
                                                 w_scale, bias_vec, alpha, v_buf, vn_buf);
  flash_kernel<<<dim3(49, 8), 256, 0, stream>>>(vn_buf, Ebf, o_part, ms_part);
  combine_coef_kernel<<<dim3(128), 256, 0, stream>>>(o_part, ms_part, v_buf, W_coef, coef_buf);
  // iter 1: b1 = delta(coef0); v1
  route_kernel<1><<<dim3(128), 256, 0, stream>>>(nullptr, b_state, e_buf, W, coef_buf,
                                                 w_scale, bias_vec, alpha, v_buf, vn_buf);
  flash_kernel<<<dim3(49, 8), 256, 0, stream>>>(vn_buf, Ebf, o_part, ms_part);
  combine_coef_kernel<<<dim3(128), 256, 0, stream>>>(o_part, ms_part, v_buf, W_coef, coef_buf);
  // iter 2 (final): b2 = b1 + delta(coef1); v2
  route_kernel<2><<<dim3(128), 256, 0, stream>>>(b_state, nullptr, e_buf, W, coef_buf,
                                                 w_scale, bias_vec, alpha, v_buf, vn_buf);
  logits32_kernel<<<dim3(782), 512, 0, stream>>>(vn_buf, item_emb, out);
}

// Round 13
// 799.162 us; speedup vs baseline: 1.1161x; 1.1161x over previous
//
#include <hip/hip_runtime.h>
#include <math.h>

typedef __attribute__((ext_vector_type(8))) short bf16x8;
typedef __attribute__((ext_vector_type(4))) float f32x4;
typedef __attribute__((ext_vector_type(2))) float f32x2;
typedef __attribute__((ext_vector_type(4))) unsigned short u16x4;
typedef __attribute__((ext_vector_type(2))) _Float16 f16x2;

static __device__ __forceinline__ short f2bf(float f) {
  unsigned u = __builtin_bit_cast(unsigned, f);
  u += 0x7fffu + ((u >> 16) & 1u);
  return (short)(u >> 16);
}
static __device__ __forceinline__ float bf2f(unsigned short s) {
  unsigned u = ((unsigned)s) << 16;
  return __builtin_bit_cast(float, u);
}
static __device__ __forceinline__ f32x4 mfma16(bf16x8 a, bf16x8 b, f32x4 c) {
  return __builtin_amdgcn_mfma_f32_16x16x32_bf16(a, b, c, 0, 0, 0);
}
static __device__ __forceinline__ bf16x8 pack8v(f32x4 a, f32x4 b) {
  bf16x8 r;
  r[0]=f2bf(a[0]); r[1]=f2bf(a[1]); r[2]=f2bf(a[2]); r[3]=f2bf(a[3]);
  r[4]=f2bf(b[0]); r[5]=f2bf(b[1]); r[6]=f2bf(b[2]); r[7]=f2bf(b[3]);
  return r;
}
static __device__ __forceinline__ float fastrcp(float x) {
  float r;
  asm("v_rcp_f32_e32 %0, %1" : "=v"(r) : "v"(x));
  return r;
}
static __device__ __forceinline__ float dot4(f32x4 a, f32x4 b) {
  return a[0]*b[0] + a[1]*b[1] + a[2]*b[2] + a[3]*b[3];
}

#define LGKM_BARRIER() do {                                   \
    asm volatile("s_waitcnt lgkmcnt(0)" ::: "memory");        \
    __builtin_amdgcn_s_barrier();                             \
    __builtin_amdgcn_sched_barrier(0);                        \
  } while (0)

// ---------------- gi = x @ Wih^T, compact 4-row quad tiles (700 blocks x 16 tiles) ----------------
__global__ __launch_bounds__(512) void gi_gemm_kernel(
    const int* __restrict__ seq0, const int* __restrict__ seq1,
    const int* __restrict__ seq2, const int* __restrict__ seq3,
    const float* __restrict__ item_emb, const float* __restrict__ Wih,
    unsigned short* __restrict__ gi_t50, unsigned short* __restrict__ gi_click)
{
  const int b = blockIdx.x;
  int beh, tile0;
  if (b < 100)      { beh = 0; tile0 = b * 16; }
  else if (b < 200) { beh = 1; tile0 = (b - 100) * 16; }
  else if (b < 300) { beh = 2; tile0 = (b - 200) * 16; }
  else              { beh = 3; tile0 = (b - 300) * 16; }
  const int T = (beh == 3) ? 200 : 50;
  const int* seq = (beh == 0) ? seq0 : (beh == 1) ? seq1 : (beh == 2) ? seq2 : seq3;
  unsigned short* gibase = (beh == 3) ? gi_click : (gi_t50 + (size_t)beh * 9830400);

  const int tid = threadIdx.x;
  const int wave = tid >> 6, lane = tid & 63, lrow = lane & 15, lk8 = lane >> 4;
  const int bcol = wave * 16 + lrow;

  bf16x8 wif[3][4];
  const float* WihB = Wih + (size_t)beh * 384 * 128;
#pragma unroll
  for (int g = 0; g < 3; ++g) {
    const int wr = g * 128 + bcol;
#pragma unroll
    for (int kt = 0; kt < 4; ++kt) {
      const int k0 = kt * 32 + lk8 * 8;
      f32x4 a0 = *(const f32x4*)(WihB + (size_t)wr * 128 + k0);
      f32x4 a1 = *(const f32x4*)(WihB + (size_t)wr * 128 + k0 + 4);
      wif[g][kt] = pack8v(a0, a1);
    }
  }

  __shared__ short xt[16][132];
  const int gj = tid >> 5;
  const int gc = (tid & 31) * 4;

  for (int ti = 0; ti < 16; ++ti) {
    const int tile = tile0 + ti;
    const int r0blk = tile / T;
    const int t = tile - r0blk * T;
    {
      const int sidx = seq[(size_t)(r0blk * 16 + gj) * T + t];
      const f32x4 xv = *(const f32x4*)(item_emb + (size_t)sidx * 128 + gc);
      xt[gj][gc]     = f2bf(xv[0]);
      xt[gj][gc + 1] = f2bf(xv[1]);
      xt[gj][gc + 2] = f2bf(xv[2]);
      xt[gj][gc + 3] = f2bf(xv[3]);
    }
    __syncthreads();
    bf16x8 ax[4];
#pragma unroll
    for (int kt = 0; kt < 4; ++kt)
      ax[kt] = *(const bf16x8*)&xt[lrow][kt * 32 + lk8 * 8];
    f32x4 acc[3] = {{0,0,0,0},{0,0,0,0},{0,0,0,0}};
#pragma unroll
    for (int kt = 0; kt < 4; ++kt) {
      acc[0] = mfma16(ax[kt], wif[0][kt], acc[0]);
      acc[1] = mfma16(ax[kt], wif[1][kt], acc[1]);
      acc[2] = mfma16(ax[kt], wif[2][kt], acc[2]);
    }
    unsigned short* base = gibase + ((size_t)(r0blk * 4 + lk8) * T + t) * 1536;
    unsigned short* dst = base + bcol * 4;
#pragma unroll
    for (int g = 0; g < 3; ++g) {
      u16x4 o;
      o[0] = (unsigned short)f2bf(acc[g][0]);
      o[1] = (unsigned short)f2bf(acc[g][1]);
      o[2] = (unsigned short)f2bf(acc[g][2]);
      o[3] = (unsigned short)f2bf(acc[g][3]);
      *(u16x4*)(dst + g * 512) = o;
    }
    __syncthreads();
  }
}

// ---------------- GRU recurrence: 2 independent 4-row chains per block, one barrier serves both ----------------
// blocks 0..63 click pairs, 64..255 t50 pairs, 256..383 Ebf workers
__global__ __launch_bounds__(256, 1) void gru_rec7_kernel(
    const float* __restrict__ Whh, const float* __restrict__ bih,
    const float* __restrict__ bhh,
    const unsigned short* __restrict__ gi_t50,
    const unsigned short* __restrict__ gi_click,
    const float* __restrict__ item_emb, unsigned short* __restrict__ Ebf,
    float* __restrict__ e_out)
{
  __shared__ short hA0[16][140];
  __shared__ short hA1[16][140];
  __shared__ short hB0[16][140];
  __shared__ short hB1[16][140];
  const int tid = threadIdx.x;

  if (blockIdx.x >= 256) {
    // workers: cast item_emb -> Ebf bf16 row-major [50048][128], pad rows zeroed
    const int wb = blockIdx.x - 256;
    for (size_t i8 = (size_t)(wb * 256 + tid) * 8; i8 < 50048u * 128u; i8 += 32768u * 8u) {
      const int row = (int)(i8 >> 7);
      bf16x8 o = {0,0,0,0,0,0,0,0};
      if (row < 50001) {
        const f32x4 a = *(const f32x4*)(item_emb + i8);
        const f32x4 b = *(const f32x4*)(item_emb + i8 + 4);
        o = pack8v(a, b);
      }
      *(bf16x8*)(Ebf + i8) = o;
    }
    return;
  }

  int beh, pr;
  if (blockIdx.x < 64) { beh = 3; pr = blockIdx.x; }
  else { beh = (blockIdx.x - 64) >> 6; pr = (blockIdx.x - 64) & 63; }
  const int T = (beh == 3) ? 200 : 50;
  const int qA = pr * 2, qB = pr * 2 + 1;
  const unsigned short* gibase =
      (beh == 3) ? gi_click : (gi_t50 + (size_t)beh * 9830400);
  const unsigned short* gibA = gibase + (size_t)qA * T * 1536;
  const unsigned short* gibB = gibase + (size_t)qB * T * 1536;

  const int w = tid >> 6;
  const int lane = tid & 63;
  const int lrow = lane & 15;
  const int lk8 = lane >> 4;
  const int col0 = w * 32 + lrow;
  const int col1 = col0 + 16;

  // Whh B-fragments shared by both chains (same behavior): 96 VGPR
  bf16x8 whf[3][2][4];
  const float* WhhB = Whh + (size_t)beh * 384 * 128;
#pragma unroll
  for (int g = 0; g < 3; ++g) {
#pragma unroll
    for (int ct = 0; ct < 2; ++ct) {
      const int wr = g * 128 + (ct ? col1 : col0);
#pragma unroll
      for (int kt = 0; kt < 4; ++kt) {
        const int k0 = kt * 32 + lk8 * 8;
        f32x4 b0 = *(const f32x4*)(WhhB + (size_t)wr * 128 + k0);
        f32x4 b1 = *(const f32x4*)(WhhB + (size_t)wr * 128 + k0 + 4);
        whf[g][ct][kt] = pack8v(b0, b1);
      }
    }
  }
  float bR[2], bZ[2], bN[2], bHN[2];
#pragma unroll
  for (int ct = 0; ct < 2; ++ct) {
    const int c = ct ? col1 : col0;
    bR[ct]  = bih[beh * 384 + c] + bhh[beh * 384 + c];
    bZ[ct]  = bih[beh * 384 + 128 + c] + bhh[beh * 384 + 128 + c];
    bN[ct]  = bih[beh * 384 + 256 + c];
    bHN[ct] = bhh[beh * 384 + 256 + c];
  }

  for (int i = tid; i < 16 * 140; i += 256) {
    ((short*)hA0)[i] = 0; ((short*)hA1)[i] = 0;
    ((short*)hB0)[i] = 0; ((short*)hB1)[i] = 0;
  }
  float hregA[2] = {0.f, 0.f}, hregB[2] = {0.f, 0.f};
  __syncthreads();

  const unsigned short* gpA0 = gibA + col0 * 4 + lk8;
  const unsigned short* gpA1 = gibA + col1 * 4 + lk8;
  const unsigned short* gpB0 = gibB + col0 * 4 + lk8;
  const unsigned short* gpB1 = gibB + col1 * 4 + lk8;

  unsigned short cAa[30], cAb[30], cBa[30], cBb[30];

#define LOAD_CHUNK2(BA, BB, C0) do {                                          \
    _Pragma("unroll")                                                         \
    for (int _s = 0; _s < 5; ++_s) {                                          \
      const size_t _o = (size_t)((C0) + _s) * 1536;                           \
      _Pragma("unroll")                                                       \
      for (int _g = 0; _g < 3; ++_g) {                                        \
        BA[_s * 6 + 0 * 3 + _g] = gpA0[_o + _g * 512];                        \
        BA[_s * 6 + 1 * 3 + _g] = gpA1[_o + _g * 512];                        \
        BB[_s * 6 + 0 * 3 + _g] = gpB0[_o + _g * 512];                        \
        BB[_s * 6 + 1 * 3 + _g] = gpB1[_o + _g * 512];                        \
      }                                                                       \
    }                                                                         \
  } while (0)

  short (*hinA)[140] = hA0;
  short (*houtA)[140] = hA1;
  short (*hinB)[140] = hB0;
  short (*houtB)[140] = hB1;

#define EPI(BUF, S, ct, hr_, hn_, hz_, hreg_, hout_) do {                     \
    const float xr = bf2f(BUF[(S)*6 + (ct)*3 + 0]) + bR[ct] + hr_[ct][0];     \
    const float xz = bf2f(BUF[(S)*6 + (ct)*3 + 1]) + bZ[ct] + hz_[ct][0];     \
    const float ea = __expf(-xr);                                             \
    const float eb = __expf(-xz);                                             \
    const float pa = 1.f + ea, pb = 1.f + eb;                                 \
    const float rd = fastrcp(pa * pb);                                        \
    const float rr = pb * rd;                                                 \
    const float zz = pa * rd;                                                 \
    const float tn = bf2f(BUF[(S)*6 + (ct)*3 + 2]) + bN[ct] + rr * (hn_[ct][0] + bHN[ct]); \
    const float tt = __expf(-2.f * tn);                                       \
    const float nn = (1.f - tt) * fastrcp(1.f + tt);                          \
    hreg_[ct] = nn + zz * (hreg_[ct] - nn);                                   \
    hout_[lk8 * 4][(ct) ? col1 : col0] = f2bf(hreg_[ct]);                     \
  } while (0)

#define STEP2(BA, BB, S) do {                                                 \
    bf16x8 ahA[4], ahB[4];                                                    \
    _Pragma("unroll")                                                         \
    for (int kt = 0; kt < 4; ++kt) {                                          \
      ahA[kt] = *(const bf16x8*)&hinA[lrow][kt * 32 + lk8 * 8];               \
      ahB[kt] = *(const bf16x8*)&hinB[lrow][kt * 32 + lk8 * 8];               \
    }                                                                         \
    f32x4 hrA[2], hzA[2], hnA[2], hrB[2], hzB[2], hnB[2];                     \
    _Pragma("unroll")                                                         \
    for (int ct = 0; ct < 2; ++ct) {                                          \
      hrA[ct] = (f32x4){0,0,0,0}; hzA[ct] = (f32x4){0,0,0,0}; hnA[ct] = (f32x4){0,0,0,0}; \
      hrB[ct] = (f32x4){0,0,0,0}; hzB[ct] = (f32x4){0,0,0,0}; hnB[ct] = (f32x4){0,0,0,0}; \
      _Pragma("unroll")                                                       \
      for (int kt = 0; kt < 4; ++kt) {                                        \
        hrA[ct] = mfma16(ahA[kt], whf[0][ct][kt], hrA[ct]);                   \
        hrB[ct] = mfma16(ahB[kt], whf[0][ct][kt], hrB[ct]);                   \
        hzA[ct] = mfma16(ahA[kt], whf[1][ct][kt], hzA[ct]);                   \
        hzB[ct] = mfma16(ahB[kt], whf[1][ct][kt], hzB[ct]);                   \
        hnA[ct] = mfma16(ahA[kt], whf[2][ct][kt], hnA[ct]);                   \
        hnB[ct] = mfma16(ahB[kt], whf[2][ct][kt], hnB[ct]);                   \
      }                                                                       \
    }                                                                         \
    _Pragma("unroll")                                                         \
    for (int ct = 0; ct < 2; ++ct) {                                          \
      EPI(BA, S, ct, hrA, hnA, hzA, hregA, houtA);                            \
      EPI(BB, S, ct, hrB, hnB, hzB, hregB, houtB);                            \
    }                                                                         \
    LGKM_BARRIER();                                                           \
    short (*_t)[140];                                                         \
    _t = hinA; hinA = houtA; houtA = _t;                                      \
    _t = hinB; hinB = houtB; houtB = _t;                                      \
  } while (0)

  LOAD_CHUNK2(cAa, cBa, 0);
  for (int c = 0; c < T; c += 10) {
    if (c + 5 < T) LOAD_CHUNK2(cAb, cBb, c + 5);
    STEP2(cAa, cBa, 0); STEP2(cAa, cBa, 1); STEP2(cAa, cBa, 2);
    STEP2(cAa, cBa, 3); STEP2(cAa, cBa, 4);
    if (c + 10 < T) LOAD_CHUNK2(cAa, cBa, c + 10);
    STEP2(cAb, cBb, 0); STEP2(cAb, cBb, 1); STEP2(cAb, cBb, 2);
    STEP2(cAb, cBb, 3); STEP2(cAb, cBb, 4);
  }
#undef STEP2
#undef EPI
#undef LOAD_CHUNK2

#pragma unroll
  for (int ct = 0; ct < 2; ++ct) {
    e_out[(size_t)(qA * 4 + lk8) * 512 + (ct ? col1 : col0) * 4 + beh] = hregA[ct];
    e_out[(size_t)(qB * 4 + lk8) * 512 + (ct ? col1 : col0) * 4 + beh] = hregB[ct];
  }
}

// ---------------- route: fused b-update + softmax(c) + v + vn (b in fp16) ----------------
template<int MODE>
__global__ __launch_bounds__(256, 1) void route_kernel(
    const _Float16* __restrict__ b_old, _Float16* __restrict__ b_new,
    const float* __restrict__ e_buf, const float* __restrict__ W,
    const float* __restrict__ coef_buf,
    const float* __restrict__ w_scale, const float* __restrict__ bias_vec,
    const float* __restrict__ alpha,
    float* __restrict__ v_buf, float* __restrict__ vn_buf)
{
  __shared__ float e_lds[4][128][4];
  __shared__ float vacc[4][4][128][8];
  const int g0 = blockIdx.x * 4;
  const int tid = threadIdx.x;
  const int wv = tid >> 6, ln = tid & 63;
  const int c0 = ln * 2;
  for (int i = tid; i < 2048; i += 256) ((float*)e_lds)[i] = e_buf[(size_t)g0 * 512 + i];

  f32x4 cf[4][2][2];
  if (MODE != 0) {
#pragma unroll
    for (int g = 0; g < 4; ++g)
#pragma unroll
      for (int cc = 0; cc < 2; ++cc) {
        cf[g][cc][0] = *(const f32x4*)(coef_buf + (size_t)(g0 + g) * 1024 + (c0 + cc) * 8);
        cf[g][cc][1] = *(const f32x4*)(coef_buf + (size_t)(g0 + g) * 1024 + (c0 + cc) * 8 + 4);
      }
  }
  __syncthreads();

  f32x4 av[4][2][2];
#pragma unroll
  for (int g = 0; g < 4; ++g)
#pragma unroll
    for (int cc = 0; cc < 2; ++cc) { av[g][cc][0] = (f32x4){0,0,0,0}; av[g][cc][1] = (f32x4){0,0,0,0}; }

  const int hbeg = wv * 32;
  for (int h = hbeg; h < hbeg + 32; ++h) {
    f32x4 wr[4][2][2];
#pragma unroll
    for (int t = 0; t < 4; ++t) {
      const float* wp = W + ((size_t)(h * 4 + t) * 128 + c0) * 8;
      wr[t][0][0] = *(const f32x4*)(wp);
      wr[t][0][1] = *(const f32x4*)(wp + 4);
      wr[t][1][0] = *(const f32x4*)(wp + 8);
      wr[t][1][1] = *(const f32x4*)(wp + 12);
    }
    f16x2 bo[4];
    if (MODE == 2) {
#pragma unroll
      for (int g = 0; g < 4; ++g)
        bo[g] = *(const f16x2*)(b_old + (size_t)(g0 + g) * 16384 + h * 128 + c0);
    }
#pragma unroll
    for (int g = 0; g < 4; ++g) {
      const f32x4 ev = *(const f32x4*)&e_lds[g][h][0];
      f32x4 u[2][2];
#pragma unroll
      for (int cc = 0; cc < 2; ++cc)
#pragma unroll
        for (int dd = 0; dd < 2; ++dd)
          u[cc][dd] = ev[0]*wr[0][cc][dd] + ev[1]*wr[1][cc][dd]
                    + ev[2]*wr[2][cc][dd] + ev[3]*wr[3][cc][dd];
      float cv0, cv1;
      if (MODE == 0) {
        cv0 = 0.0078125f; cv1 = 0.0078125f;
      } else {
        float b0 = dot4(u[0][0], cf[g][0][0]) + dot4(u[0][1], cf[g][0][1]);
        float b1 = dot4(u[1][0], cf[g][1][0]) + dot4(u[1][1], cf[g][1][1]);
        if (MODE == 2) { b0 += (float)bo[g][0]; b1 += (float)bo[g][1]; }
        if (MODE == 1) {
          f16x2 bw; bw[0] = (_Float16)b0; bw[1] = (_Float16)b1;
          *(f16x2*)(b_new + (size_t)(g0 + g) * 16384 + h * 128 + c0) = bw;
        }
        float m = fmaxf(b0, b1);
#pragma unroll
        for (int off = 32; off > 0; off >>= 1) m = fmaxf(m, __shfl_xor(m, off));
        const float e0 = __expf(b0 - m), e1 = __expf(b1 - m);
        float s = e0 + e1;
#pragma unroll
        for (int off = 32; off > 0; off >>= 1) s += __shfl_xor(s, off);
        const float inv = 1.f / s;
        cv0 = e0 * inv; cv1 = e1 * inv;
      }
      av[g][0][0] += cv0 * u[0][0]; av[g][0][1] += cv0 * u[0][1];
      av[g][1][0] += cv1 * u[1][0]; av[g][1][1] += cv1 * u[1][1];
    }
  }
#pragma unroll
  for (int g = 0; g < 4; ++g)
#pragma unroll
    for (int cc = 0; cc < 2; ++cc) {
      *(f32x4*)&vacc[wv][g][c0 + cc][0] = av[g][cc][0];
      *(f32x4*)&vacc[wv][g][c0 + cc][4] = av[g][cc][1];
    }
  __syncthreads();

  const float al = alpha[0];
  const int rg = tid >> 6;
  const int rc = (tid & 63) * 2;
#pragma unroll
  for (int cc = 0; cc < 2; ++cc) {
    const int c = rc + cc;
    f32x4 s0 = *(const f32x4*)&vacc[0][rg][c][0];
    f32x4 s1 = *(const f32x4*)&vacc[0][rg][c][4];
#pragma unroll
    for (int wq = 1; wq < 4; ++wq) {
      s0 += *(const f32x4*)&vacc[wq][rg][c][0];
      s1 += *(const f32x4*)&vacc[wq][rg][c][4];
    }
    s0 *= al; s1 *= al;
    *(f32x4*)(v_buf + (size_t)(g0 + rg) * 1024 + c * 8) = s0;
    *(f32x4*)(v_buf + (size_t)(g0 + rg) * 1024 + c * 8 + 4) = s1;
    const float ss = dot4(s0, s0) + dot4(s1, s1);
    vn_buf[(g0 + rg) * 128 + c] = sqrtf(ss) * w_scale[c] + bias_vec[c];
  }
}

// ---------------- flash: p-partials = softmax-stream(vn @ Ebf^T) @ Ebf ----------------
__global__ __launch_bounds__(256, 2) void flash_kernel(
    const float* __restrict__ vn, const unsigned short* __restrict__ Ebf,
    float* __restrict__ o_part, float* __restrict__ ms_part)
{
  __shared__ short e_nat[64][136];
  __shared__ short e_tr[128][72];
  __shared__ short p_lds[4][16][72];
  const int xc = blockIdx.x;
  const int tid = threadIdx.x;
  const int w = tid >> 6, lane = tid & 63, lrow = lane & 15, lk8 = lane >> 4;
  const int rowbase = blockIdx.y * 64 + w * 16;

  bf16x8 qf[4];
#pragma unroll
  for (int kt = 0; kt < 4; ++kt) {
    const float* p = vn + (size_t)(rowbase + lrow) * 128 + kt * 32 + lk8 * 8;
    qf[kt] = pack8v(*(const f32x4*)p, *(const f32x4*)(p + 4));
  }

  f32x4 o_acc[8] = {{0,0,0,0},{0,0,0,0},{0,0,0,0},{0,0,0,0},
                    {0,0,0,0},{0,0,0,0},{0,0,0,0},{0,0,0,0}};
  float m_run[4] = {-1e30f, -1e30f, -1e30f, -1e30f};
  float s_run[4] = {0.f, 0.f, 0.f, 0.f};

  const int kbeg = xc * 1024;
  const int nst = (kbeg + 1024 <= 50048) ? 16 : (50048 - kbeg) / 64;
  const int sr = tid >> 2, sseg = (tid & 3) * 32;

  for (int st = 0; st < nst; ++st) {
    const int v0 = kbeg + st * 64;
    {
      bf16x8 ev[4];
#pragma unroll
      for (int q = 0; q < 4; ++q)
        ev[q] = *(const bf16x8*)(Ebf + (size_t)(v0 + sr) * 128 + sseg + q * 8);
#pragma unroll
      for (int q = 0; q < 4; ++q)
        *(bf16x8*)&e_nat[sr][sseg + q * 8] = ev[q];
#pragma unroll
      for (int q = 0; q < 4; ++q)
#pragma unroll
        for (int j = 0; j < 8; ++j)
          e_tr[sseg + q * 8 + j][sr] = ev[q][j];
    }
    __syncthreads();
    f32x4 sacc[4] = {{0,0,0,0},{0,0,0,0},{0,0,0,0},{0,0,0,0}};
#pragma unroll
    for (int kt = 0; kt < 4; ++kt) {
#pragma unroll
      for (int nt = 0; nt < 4; ++nt) {
        const bf16x8 bfr = *(const bf16x8*)&e_nat[nt * 16 + lrow][kt * 32 + lk8 * 8];
        sacc[nt] = mfma16(qf[kt], bfr, sacc[nt]);
      }
    }
    if (v0 + 64 > 50001) {
#pragma unroll
      for (int nt = 0; nt < 4; ++nt)
        if (v0 + nt * 16 + lrow >= 50001)
          sacc[nt] = (f32x4){-1e30f, -1e30f, -1e30f, -1e30f};
    }
#pragma unroll
    for (int e2 = 0; e2 < 4; ++e2) {
      float mt = fmaxf(fmaxf(sacc[0][e2], sacc[1][e2]), fmaxf(sacc[2][e2], sacc[3][e2]));
      mt = fmaxf(mt, __shfl_xor(mt, 1));
      mt = fmaxf(mt, __shfl_xor(mt, 2));
      mt = fmaxf(mt, __shfl_xor(mt, 4));
      mt = fmaxf(mt, __shfl_xor(mt, 8));
      const float mn = fmaxf(m_run[e2], mt);
      const float scale = __expf(m_run[e2] - mn);
      m_run[e2] = mn;
      float pv[4];
#pragma unroll
      for (int nt = 0; nt < 4; ++nt) pv[nt] = __expf(sacc[nt][e2] - mn);
      float ps = pv[0] + pv[1] + pv[2] + pv[3];
      ps += __shfl_xor(ps, 1);
      ps += __shfl_xor(ps, 2);
      ps += __shfl_xor(ps, 4);
      ps += __shfl_xor(ps, 8);
      s_run[e2] = s_run[e2] * scale + ps;
#pragma unroll
      for (int nt8 = 0; nt8 < 8; ++nt8) o_acc[nt8][e2] *= scale;
#pragma unroll
      for (int nt = 0; nt < 4; ++nt)
        p_lds[w][lk8 * 4 + e2][nt * 16 + lrow] = f2bf(pv[nt]);
    }
#pragma unroll
    for (int kt2 = 0; kt2 < 2; ++kt2) {
      const bf16x8 pa = *(const bf16x8*)&p_lds[w][lrow][kt2 * 32 + lk8 * 8];
#pragma unroll
      for (int nt8 = 0; nt8 < 8; ++nt8) {
        const bf16x8 bfr = *(const bf16x8*)&e_tr[nt8 * 16 + lrow][kt2 * 32 + lk8 * 8];
        o_acc[nt8] = mfma16(pa, bfr, o_acc[nt8]);
      }
    }
    __syncthreads();
  }

#pragma unroll
  for (int nt8 = 0; nt8 < 8; ++nt8)
#pragma unroll
    for (int e2 = 0; e2 < 4; ++e2)
      o_part[((size_t)xc * 512 + rowbase + lk8 * 4 + e2) * 128 + nt8 * 16 + lrow] = o_acc[nt8][e2];
  if (lrow == 0) {
#pragma unroll
    for (int e2 = 0; e2 < 4; ++e2) {
      const int row = rowbase + lk8 * 4 + e2;
      ms_part[((size_t)row * 49 + xc) * 2]     = m_run[e2];
      ms_part[((size_t)row * 49 + xc) * 2 + 1] = s_run[e2];
    }
  }
}

// ---------------- combine partials -> p, then coef = concat(p, v) @ W_coef ----------------
__global__ __launch_bounds__(256) void combine_coef_kernel(
    const float* __restrict__ o_part, const float* __restrict__ ms_part,
    const float* __restrict__ v_buf, const float* __restrict__ W_coef,
    float* __restrict__ coef_buf)
{
  __shared__ float wg[4][64];
  __shared__ float p_s[4][128];
  const int g0 = blockIdx.x * 4;
  const int tid = threadIdx.x;
  const int w = tid >> 6, lane = tid & 63;
  {
    const int row = g0 + w;
    float ml = -1e30f, sl = 0.f;
    if (lane < 49) {
      ml = ms_part[((size_t)row * 49 + lane) * 2];
      sl = ms_part[((size_t)row * 49 + lane) * 2 + 1];
    }
    float M = ml;
#pragma unroll
    for (int off = 32; off > 0; off >>= 1) M = fmaxf(M, __shfl_xor(M, off));
    float e = (lane < 49) ? sl * __expf(ml - M) : 0.f;
    float S = e;
#pragma unroll
    for (int off = 32; off > 0; off >>= 1) S += __shfl_xor(S, off);
    const float inv = 1.f / S;
    if (lane < 49) wg[w][lane] = __expf(ml - M) * inv;
  }
  __syncthreads();
  {
    const int d = tid & 127, gh = tid >> 7;
    for (int gg = gh; gg < 4; gg += 2) {
      const int row = g0 + gg;
      float acc = 0.f;
      for (int x = 0; x < 49; ++x)
        acc += o_part[((size_t)x * 512 + row) * 128 + d] * wg[gg][x];
      p_s[gg][d] = acc;
    }
  }
  __syncthreads();
  const int c = tid >> 1, dh = (tid & 1) * 4;
  float vg[4][8];
#pragma unroll
  for (int g = 0; g < 4; ++g) {
    const f32x4 va = *(const f32x4*)(v_buf + (size_t)(g0 + g) * 1024 + c * 8);
    const f32x4 vb = *(const f32x4*)(v_buf + (size_t)(g0 + g) * 1024 + c * 8 + 4);
    vg[g][0]=va[0]; vg[g][1]=va[1]; vg[g][2]=va[2]; vg[g][3]=va[3];
    vg[g][4]=vb[0]; vg[g][5]=vb[1]; vg[g][6]=vb[2]; vg[g][7]=vb[3];
  }
  const float* wc = W_coef + (size_t)c * 1088 + dh;
  f32x4 acc4[4] = {{0,0,0,0},{0,0,0,0},{0,0,0,0},{0,0,0,0}};
  for (int dp = 0; dp < 128; ++dp) {
    const f32x4 w4 = *(const f32x4*)(wc + (size_t)dp * 8);
#pragma unroll
    for (int g = 0; g < 4; ++g) acc4[g] += p_s[g][dp] * w4;
  }
#pragma unroll
  for (int q = 0; q < 8; ++q) {
    const f32x4 w4 = *(const f32x4*)(wc + (size_t)(128 + q) * 8);
#pragma unroll
    for (int g = 0; g < 4; ++g) acc4[g] += vg[g][q] * w4;
  }
#pragma unroll
  for (int g = 0; g < 4; ++g)
    *(f32x4*)(coef_buf + (size_t)(g0 + g) * 1024 + c * 8 + dh) = acc4[g];
}

// ---------------- final logits fp32 into d_out (stages from fp32 item_emb) ----------------
__global__ __launch_bounds__(512) void logits32_kernel(
    const float* __restrict__ vn, const float* __restrict__ E,
    float* __restrict__ out)
{
  __shared__ short et[64][136];
  const int n0 = blockIdx.x * 64;
  const int tid = threadIdx.x;
  const int wave = tid >> 6, lane = tid & 63, lrow = lane & 15, lk8 = lane >> 4;
  {
    const int r = tid >> 3, ks = (tid & 7) * 16;
    const int v = n0 + r;
    f32x4 a = {0,0,0,0}, b = {0,0,0,0}, c = {0,0,0,0}, d = {0,0,0,0};
    if (v < 50001) {
      const float* p = E + (size_t)v * 128 + ks;
      a = *(const f32x4*)p; b = *(const f32x4*)(p + 4);
      c = *(const f32x4*)(p + 8); d = *(const f32x4*)(p + 12);
    }
    *(bf16x8*)&et[r][ks] = pack8v(a, b);
    *(bf16x8*)&et[r][ks + 8] = pack8v(c, d);
  }
  __syncthreads();
  for (int mb = 0; mb < 4; ++mb) {
    const int m0 = mb * 128;
    const int arow = m0 + wave * 16 + lrow;
    bf16x8 afr[4];
#pragma unroll
    for (int kt = 0; kt < 4; ++kt) {
      const float* p = vn + (size_t)arow * 128 + kt * 32 + lk8 * 8;
      afr[kt] = pack8v(*(const f32x4*)p, *(const f32x4*)(p + 4));
    }
    f32x4 acc[4] = {{0,0,0,0},{0,0,0,0},{0,0,0,0},{0,0,0,0}};
#pragma unroll
    for (int kt = 0; kt < 4; ++kt) {
#pragma unroll
      for (int nt = 0; nt < 4; ++nt) {
        const bf16x8 bfr = *(const bf16x8*)&et[nt * 16 + lrow][kt * 32 + lk8 * 8];
        acc[nt] = mfma16(afr[kt], bfr, acc[nt]);
      }
    }
#pragma unroll
    for (int nt = 0; nt < 4; ++nt) {
      const int col = n0 + nt * 16 + lrow;
      if (col < 50001) {
        const int row = m0 + wave * 16 + lk8 * 4;
#pragma unroll
        for (int e2 = 0; e2 < 4; ++e2)
          out[(size_t)(row + e2) * 50001 + col] = acc[nt][e2];
      }
    }
  }
}

extern "C" void kernel_launch(void* const* d_in, const int* in_sizes, int n_in,
                              void* d_out, int out_size, void* d_ws, size_t ws_size,
                              hipStream_t stream) {
  const int* seq0 = (const int*)d_in[0];
  const int* seq1 = (const int*)d_in[1];
  const int* seq2 = (const int*)d_in[2];
  const int* seq3 = (const int*)d_in[3];
  const float* item_emb = (const float*)d_in[4];
  const float* Wih = (const float*)d_in[5];
  const float* Whh = (const float*)d_in[6];
  const float* bih = (const float*)d_in[7];
  const float* bhh = (const float*)d_in[8];
  const float* W = (const float*)d_in[9];
  const float* w_scale = (const float*)d_in[10];
  const float* bias_vec = (const float*)d_in[11];
  const float* alpha = (const float*)d_in[12];
  const float* W_coef = (const float*)d_in[13];
  float* out = (float*)d_out;

  char* ws = (char*)d_ws;
  float* e_buf       = (float*)(ws);               // 1 MB
  _Float16* b_state  = (_Float16*)(ws + 1048576);  // 16.7 MB (fp16)
  float* v_buf    = (float*)(ws + 34603008);       // 2 MB
  float* vn_buf   = (float*)(ws + 36700160);       // 256 KB
  float* coef_buf = (float*)(ws + 37224448);       // 2 MB
  float* o_part   = (float*)(ws + 39325696);       // 12.85 MB
  float* ms_part  = (float*)(ws + 52170752);       // 200 KB

  unsigned short* gi_t50   = (unsigned short*)(ws + 1048576);  // 57.6 MB overlay
  unsigned short* gi_click = (unsigned short*)d_out;           // 76.8 MB in d_out
  unsigned short* Ebf = (unsigned short*)((char*)d_out + 78643200);  // 12.8 MB tail

  gi_gemm_kernel<<<dim3(700), 512, 0, stream>>>(seq0, seq1, seq2, seq3, item_emb, Wih,
                                                gi_t50, gi_click);
  gru_rec7_kernel<<<dim3(384), 256, 0, stream>>>(Whh, bih, bhh, gi_t50, gi_click,
                                                 item_emb, Ebf, e_buf);
  // iter 0: c uniform
  route_kernel<0><<<dim3(128), 256, 0, stream>>>(nullptr, nullptr, e_buf, W, nullptr,
                                                 w_scale, bias_vec, alpha, v_buf, vn_buf);
  flash_kernel<<<dim3(49, 8), 256, 0, stream>>>(vn_buf, Ebf, o_part, ms_part);
  combine_coef_kernel<<<dim3(128), 256, 0, stream>>>(o_part, ms_part, v_buf, W_coef, coef_buf);
  // iter 1: b1 = delta(coef0); v1
  route_kernel<1><<<dim3(128), 256, 0, stream>>>(nullptr, b_state, e_buf, W, coef_buf,
                                                 w_scale, bias_vec, alpha, v_buf, vn_buf);
  flash_kernel<<<dim3(49, 8), 256, 0, stream>>>(vn_buf, Ebf, o_part, ms_part);
  combine_coef_kernel<<<dim3(128), 256, 0, stream>>>(o_part, ms_part, v_buf, W_coef, coef_buf);
  // iter 2 (final): b2 = b1 + delta(coef1); v2
  route_kernel<2><<<dim3(128), 256, 0, stream>>>(b_state, nullptr, e_buf, W, coef_buf,
                                                 w_scale, bias_vec, alpha, v_buf, vn_buf);
  logits32_kernel<<<dim3(782), 512, 0, stream>>>(vn_buf, item_emb, out);
}

// Round 14
// 798.057 us; speedup vs baseline: 1.1177x; 1.0014x over previous
//
#include <hip/hip_runtime.h>
#include <math.h>

typedef __attribute__((ext_vector_type(8))) short bf16x8;
typedef __attribute__((ext_vector_type(4))) float f32x4;
typedef __attribute__((ext_vector_type(2))) float f32x2;
typedef __attribute__((ext_vector_type(4))) unsigned short u16x4;
typedef __attribute__((ext_vector_type(2))) _Float16 f16x2;

static __device__ __forceinline__ short f2bf(float f) {
  unsigned u = __builtin_bit_cast(unsigned, f);
  u += 0x7fffu + ((u >> 16) & 1u);
  return (short)(u >> 16);
}
static __device__ __forceinline__ float bf2f(unsigned short s) {
  unsigned u = ((unsigned)s) << 16;
  return __builtin_bit_cast(float, u);
}
static __device__ __forceinline__ f32x4 mfma16(bf16x8 a, bf16x8 b, f32x4 c) {
  return __builtin_amdgcn_mfma_f32_16x16x32_bf16(a, b, c, 0, 0, 0);
}
static __device__ __forceinline__ bf16x8 pack8v(f32x4 a, f32x4 b) {
  bf16x8 r;
  r[0]=f2bf(a[0]); r[1]=f2bf(a[1]); r[2]=f2bf(a[2]); r[3]=f2bf(a[3]);
  r[4]=f2bf(b[0]); r[5]=f2bf(b[1]); r[6]=f2bf(b[2]); r[7]=f2bf(b[3]);
  return r;
}
static __device__ __forceinline__ float fastrcp(float x) {
  float r;
  asm("v_rcp_f32_e32 %0, %1" : "=v"(r) : "v"(x));
  return r;
}
static __device__ __forceinline__ float dot4(f32x4 a, f32x4 b) {
  return a[0]*b[0] + a[1]*b[1] + a[2]*b[2] + a[3]*b[3];
}

#define LGKM_BARRIER() do {                                   \
    asm volatile("s_waitcnt lgkmcnt(0)" ::: "memory");        \
    __builtin_amdgcn_s_barrier();                             \
    __builtin_amdgcn_sched_barrier(0);                        \
  } while (0)

// ---------------- gi = x @ Wih^T, compact 4-row quad tiles (700 blocks x 16 tiles) ----------------
__global__ __launch_bounds__(512) void gi_gemm_kernel(
    const int* __restrict__ seq0, const int* __restrict__ seq1,
    const int* __restrict__ seq2, const int* __restrict__ seq3,
    const float* __restrict__ item_emb, const float* __restrict__ Wih,
    unsigned short* __restrict__ gi_t50, unsigned short* __restrict__ gi_click)
{
  const int b = blockIdx.x;
  int beh, tile0;
  if (b < 100)      { beh = 0; tile0 = b * 16; }
  else if (b < 200) { beh = 1; tile0 = (b - 100) * 16; }
  else if (b < 300) { beh = 2; tile0 = (b - 200) * 16; }
  else              { beh = 3; tile0 = (b - 300) * 16; }
  const int T = (beh == 3) ? 200 : 50;
  const int* seq = (beh == 0) ? seq0 : (beh == 1) ? seq1 : (beh == 2) ? seq2 : seq3;
  unsigned short* gibase = (beh == 3) ? gi_click : (gi_t50 + (size_t)beh * 9830400);

  const int tid = threadIdx.x;
  const int wave = tid >> 6, lane = tid & 63, lrow = lane & 15, lk8 = lane >> 4;
  const int bcol = wave * 16 + lrow;

  bf16x8 wif[3][4];
  const float* WihB = Wih + (size_t)beh * 384 * 128;
#pragma unroll
  for (int g = 0; g < 3; ++g) {
    const int wr = g * 128 + bcol;
#pragma unroll
    for (int kt = 0; kt < 4; ++kt) {
      const int k0 = kt * 32 + lk8 * 8;
      f32x4 a0 = *(const f32x4*)(WihB + (size_t)wr * 128 + k0);
      f32x4 a1 = *(const f32x4*)(WihB + (size_t)wr * 128 + k0 + 4);
      wif[g][kt] = pack8v(a0, a1);
    }
  }

  __shared__ short xt[16][132];
  const int gj = tid >> 5;
  const int gc = (tid & 31) * 4;

  for (int ti = 0; ti < 16; ++ti) {
    const int tile = tile0 + ti;
    const int r0blk = tile / T;
    const int t = tile - r0blk * T;
    {
      const int sidx = seq[(size_t)(r0blk * 16 + gj) * T + t];
      const f32x4 xv = *(const f32x4*)(item_emb + (size_t)sidx * 128 + gc);
      xt[gj][gc]     = f2bf(xv[0]);
      xt[gj][gc + 1] = f2bf(xv[1]);
      xt[gj][gc + 2] = f2bf(xv[2]);
      xt[gj][gc + 3] = f2bf(xv[3]);
    }
    __syncthreads();
    bf16x8 ax[4];
#pragma unroll
    for (int kt = 0; kt < 4; ++kt)
      ax[kt] = *(const bf16x8*)&xt[lrow][kt * 32 + lk8 * 8];
    f32x4 acc[3] = {{0,0,0,0},{0,0,0,0},{0,0,0,0}};
#pragma unroll
    for (int kt = 0; kt < 4; ++kt) {
      acc[0] = mfma16(ax[kt], wif[0][kt], acc[0]);
      acc[1] = mfma16(ax[kt], wif[1][kt], acc[1]);
      acc[2] = mfma16(ax[kt], wif[2][kt], acc[2]);
    }
    unsigned short* base = gibase + ((size_t)(r0blk * 4 + lk8) * T + t) * 1536;
    unsigned short* dst = base + bcol * 4;
#pragma unroll
    for (int g = 0; g < 3; ++g) {
      u16x4 o;
      o[0] = (unsigned short)f2bf(acc[g][0]);
      o[1] = (unsigned short)f2bf(acc[g][1]);
      o[2] = (unsigned short)f2bf(acc[g][2]);
      o[3] = (unsigned short)f2bf(acc[g][3]);
      *(u16x4*)(dst + g * 512) = o;
    }
    __syncthreads();
  }
}

// ---------------- GRU recurrence: 2 independent 4-row chains per block, one barrier serves both ----------------
// blocks 0..63 click pairs, 64..255 t50 pairs, 256..383 Ebf workers
__global__ __launch_bounds__(256, 1) void gru_rec7_kernel(
    const float* __restrict__ Whh, const float* __restrict__ bih,
    const float* __restrict__ bhh,
    const unsigned short* __restrict__ gi_t50,
    const unsigned short* __restrict__ gi_click,
    const float* __restrict__ item_emb, unsigned short* __restrict__ Ebf,
    float* __restrict__ e_out)
{
  __shared__ short hA0[16][140];
  __shared__ short hA1[16][140];
  __shared__ short hB0[16][140];
  __shared__ short hB1[16][140];
  const int tid = threadIdx.x;

  if (blockIdx.x >= 256) {
    // workers: cast item_emb -> Ebf bf16 row-major [50048][128], pad rows zeroed
    const int wb = blockIdx.x - 256;
    for (size_t i8 = (size_t)(wb * 256 + tid) * 8; i8 < 50048u * 128u; i8 += 32768u * 8u) {
      const int row = (int)(i8 >> 7);
      bf16x8 o = {0,0,0,0,0,0,0,0};
      if (row < 50001) {
        const f32x4 a = *(const f32x4*)(item_emb + i8);
        const f32x4 b = *(const f32x4*)(item_emb + i8 + 4);
        o = pack8v(a, b);
      }
      *(bf16x8*)(Ebf + i8) = o;
    }
    return;
  }

  int beh, pr;
  if (blockIdx.x < 64) { beh = 3; pr = blockIdx.x; }
  else { beh = (blockIdx.x - 64) >> 6; pr = (blockIdx.x - 64) & 63; }
  const int T = (beh == 3) ? 200 : 50;
  const int qA = pr * 2, qB = pr * 2 + 1;
  const unsigned short* gibase =
      (beh == 3) ? gi_click : (gi_t50 + (size_t)beh * 9830400);
  const unsigned short* gibA = gibase + (size_t)qA * T * 1536;
  const unsigned short* gibB = gibase + (size_t)qB * T * 1536;

  const int w = tid >> 6;
  const int lane = tid & 63;
  const int lrow = lane & 15;
  const int lk8 = lane >> 4;
  const int col0 = w * 32 + lrow;
  const int col1 = col0 + 16;

  // Whh B-fragments shared by both chains (same behavior): 96 VGPR
  bf16x8 whf[3][2][4];
  const float* WhhB = Whh + (size_t)beh * 384 * 128;
#pragma unroll
  for (int g = 0; g < 3; ++g) {
#pragma unroll
    for (int ct = 0; ct < 2; ++ct) {
      const int wr = g * 128 + (ct ? col1 : col0);
#pragma unroll
      for (int kt = 0; kt < 4; ++kt) {
        const int k0 = kt * 32 + lk8 * 8;
        f32x4 b0 = *(const f32x4*)(WhhB + (size_t)wr * 128 + k0);
        f32x4 b1 = *(const f32x4*)(WhhB + (size_t)wr * 128 + k0 + 4);
        whf[g][ct][kt] = pack8v(b0, b1);
      }
    }
  }
  float bR[2], bZ[2], bN[2], bHN[2];
#pragma unroll
  for (int ct = 0; ct < 2; ++ct) {
    const int c = ct ? col1 : col0;
    bR[ct]  = bih[beh * 384 + c] + bhh[beh * 384 + c];
    bZ[ct]  = bih[beh * 384 + 128 + c] + bhh[beh * 384 + 128 + c];
    bN[ct]  = bih[beh * 384 + 256 + c];
    bHN[ct] = bhh[beh * 384 + 256 + c];
  }

  for (int i = tid; i < 16 * 140; i += 256) {
    ((short*)hA0)[i] = 0; ((short*)hA1)[i] = 0;
    ((short*)hB0)[i] = 0; ((short*)hB1)[i] = 0;
  }
  float hregA[2] = {0.f, 0.f}, hregB[2] = {0.f, 0.f};
  __syncthreads();

  const unsigned short* gpA0 = gibA + col0 * 4 + lk8;
  const unsigned short* gpA1 = gibA + col1 * 4 + lk8;
  const unsigned short* gpB0 = gibB + col0 * 4 + lk8;
  const unsigned short* gpB1 = gibB + col1 * 4 + lk8;

  unsigned short cAa[30], cAb[30], cBa[30], cBb[30];

#define LOAD_CHUNK2(BA, BB, C0) do {                                          \
    _Pragma("unroll")                                                         \
    for (int _s = 0; _s < 5; ++_s) {                                          \
      const size_t _o = (size_t)((C0) + _s) * 1536;                           \
      _Pragma("unroll")                                                       \
      for (int _g = 0; _g < 3; ++_g) {                                        \
        BA[_s * 6 + 0 * 3 + _g] = gpA0[_o + _g * 512];                        \
        BA[_s * 6 + 1 * 3 + _g] = gpA1[_o + _g * 512];                        \
        BB[_s * 6 + 0 * 3 + _g] = gpB0[_o + _g * 512];                        \
        BB[_s * 6 + 1 * 3 + _g] = gpB1[_o + _g * 512];                        \
      }                                                                       \
    }                                                                         \
  } while (0)

  short (*hinA)[140] = hA0;
  short (*houtA)[140] = hA1;
  short (*hinB)[140] = hB0;
  short (*houtB)[140] = hB1;

#define EPI(BUF, S, ct, hr_, hn_, hz_, hreg_, hout_) do {                     \
    const float xr = bf2f(BUF[(S)*6 + (ct)*3 + 0]) + bR[ct] + hr_[ct][0];     \
    const float xz = bf2f(BUF[(S)*6 + (ct)*3 + 1]) + bZ[ct] + hz_[ct][0];     \
    const float ea = __expf(-xr);                                             \
    const float eb = __expf(-xz);                                             \
    const float pa = 1.f + ea, pb = 1.f + eb;                                 \
    const float rd = fastrcp(pa * pb);                                        \
    const float rr = pb * rd;                                                 \
    const float zz = pa * rd;                                                 \
    const float tn = bf2f(BUF[(S)*6 + (ct)*3 + 2]) + bN[ct] + rr * (hn_[ct][0] + bHN[ct]); \
    const float tt = __expf(-2.f * tn);                                       \
    const float nn = (1.f - tt) * fastrcp(1.f + tt);                          \
    hreg_[ct] = nn + zz * (hreg_[ct] - nn);                                   \
    hout_[lk8 * 4][(ct) ? col1 : col0] = f2bf(hreg_[ct]);                     \
  } while (0)

#define STEP2(BA, BB, S) do {                                                 \
    bf16x8 ahA[4], ahB[4];                                                    \
    _Pragma("unroll")                                                         \
    for (int kt = 0; kt < 4; ++kt) {                                          \
      ahA[kt] = *(const bf16x8*)&hinA[lrow][kt * 32 + lk8 * 8];               \
      ahB[kt] = *(const bf16x8*)&hinB[lrow][kt * 32 + lk8 * 8];               \
    }                                                                         \
    f32x4 hrA[2], hzA[2], hnA[2], hrB[2], hzB[2], hnB[2];                     \
    _Pragma("unroll")                                                         \
    for (int ct = 0; ct < 2; ++ct) {                                          \
      hrA[ct] = (f32x4){0,0,0,0}; hzA[ct] = (f32x4){0,0,0,0}; hnA[ct] = (f32x4){0,0,0,0}; \
      hrB[ct] = (f32x4){0,0,0,0}; hzB[ct] = (f32x4){0,0,0,0}; hnB[ct] = (f32x4){0,0,0,0}; \
      _Pragma("unroll")                                                       \
      for (int kt = 0; kt < 4; ++kt) {                                        \
        hrA[ct] = mfma16(ahA[kt], whf[0][ct][kt], hrA[ct]);                   \
        hrB[ct] = mfma16(ahB[kt], whf[0][ct][kt], hrB[ct]);                   \
        hzA[ct] = mfma16(ahA[kt], whf[1][ct][kt], hzA[ct]);                   \
        hzB[ct] = mfma16(ahB[kt], whf[1][ct][kt], hzB[ct]);                   \
        hnA[ct] = mfma16(ahA[kt], whf[2][ct][kt], hnA[ct]);                   \
        hnB[ct] = mfma16(ahB[kt], whf[2][ct][kt], hnB[ct]);                   \
      }                                                                       \
    }                                                                         \
    _Pragma("unroll")                                                         \
    for (int ct = 0; ct < 2; ++ct) {                                          \
      EPI(BA, S, ct, hrA, hnA, hzA, hregA, houtA);                            \
      EPI(BB, S, ct, hrB, hnB, hzB, hregB, houtB);                            \
    }                                                                         \
    LGKM_BARRIER();                                                           \
    short (*_t)[140];                                                         \
    _t = hinA; hinA = houtA; houtA = _t;                                      \
    _t = hinB; hinB = houtB; houtB = _t;                                      \
  } while (0)

  LOAD_CHUNK2(cAa, cBa, 0);
  for (int c = 0; c < T; c += 10) {
    if (c + 5 < T) LOAD_CHUNK2(cAb, cBb, c + 5);
    STEP2(cAa, cBa, 0); STEP2(cAa, cBa, 1); STEP2(cAa, cBa, 2);
    STEP2(cAa, cBa, 3); STEP2(cAa, cBa, 4);
    if (c + 10 < T) LOAD_CHUNK2(cAa, cBa, c + 10);
    STEP2(cAb, cBb, 0); STEP2(cAb, cBb, 1); STEP2(cAb, cBb, 2);
    STEP2(cAb, cBb, 3); STEP2(cAb, cBb, 4);
  }
#undef STEP2
#undef EPI
#undef LOAD_CHUNK2

#pragma unroll
  for (int ct = 0; ct < 2; ++ct) {
    e_out[(size_t)(qA * 4 + lk8) * 512 + (ct ? col1 : col0) * 4 + beh] = hregA[ct];
    e_out[(size_t)(qB * 4 + lk8) * 512 + (ct ? col1 : col0) * 4 + beh] = hregB[ct];
  }
}

// ---------------- route: fused b-update + softmax(c) + v + vn (b in fp16) ----------------
template<int MODE>
__global__ __launch_bounds__(256, 1) void route_kernel(
    const _Float16* __restrict__ b_old, _Float16* __restrict__ b_new,
    const float* __restrict__ e_buf, const float* __restrict__ W,
    const float* __restrict__ coef_buf,
    const float* __restrict__ w_scale, const float* __restrict__ bias_vec,
    const float* __restrict__ alpha,
    float* __restrict__ v_buf, float* __restrict__ vn_buf)
{
  __shared__ float e_lds[4][128][4];
  __shared__ float vacc[4][4][128][8];
  const int g0 = blockIdx.x * 4;
  const int tid = threadIdx.x;
  const int wv = tid >> 6, ln = tid & 63;
  const int c0 = ln * 2;
  for (int i = tid; i < 2048; i += 256) ((float*)e_lds)[i] = e_buf[(size_t)g0 * 512 + i];

  f32x4 cf[4][2][2];
  if (MODE != 0) {
#pragma unroll
    for (int g = 0; g < 4; ++g)
#pragma unroll
      for (int cc = 0; cc < 2; ++cc) {
        cf[g][cc][0] = *(const f32x4*)(coef_buf + (size_t)(g0 + g) * 1024 + (c0 + cc) * 8);
        cf[g][cc][1] = *(const f32x4*)(coef_buf + (size_t)(g0 + g) * 1024 + (c0 + cc) * 8 + 4);
      }
  }
  __syncthreads();

  f32x4 av[4][2][2];
#pragma unroll
  for (int g = 0; g < 4; ++g)
#pragma unroll
    for (int cc = 0; cc < 2; ++cc) { av[g][cc][0] = (f32x4){0,0,0,0}; av[g][cc][1] = (f32x4){0,0,0,0}; }

  const int hbeg = wv * 32;
  for (int h = hbeg; h < hbeg + 32; ++h) {
    f32x4 wr[4][2][2];
#pragma unroll
    for (int t = 0; t < 4; ++t) {
      const float* wp = W + ((size_t)(h * 4 + t) * 128 + c0) * 8;
      wr[t][0][0] = *(const f32x4*)(wp);
      wr[t][0][1] = *(const f32x4*)(wp + 4);
      wr[t][1][0] = *(const f32x4*)(wp + 8);
      wr[t][1][1] = *(const f32x4*)(wp + 12);
    }
    f16x2 bo[4];
    if (MODE == 2) {
#pragma unroll
      for (int g = 0; g < 4; ++g)
        bo[g] = *(const f16x2*)(b_old + (size_t)(g0 + g) * 16384 + h * 128 + c0);
    }
#pragma unroll
    for (int g = 0; g < 4; ++g) {
      const f32x4 ev = *(const f32x4*)&e_lds[g][h][0];
      f32x4 u[2][2];
#pragma unroll
      for (int cc = 0; cc < 2; ++cc)
#pragma unroll
        for (int dd = 0; dd < 2; ++dd)
          u[cc][dd] = ev[0]*wr[0][cc][dd] + ev[1]*wr[1][cc][dd]
                    + ev[2]*wr[2][cc][dd] + ev[3]*wr[3][cc][dd];
      float cv0, cv1;
      if (MODE == 0) {
        cv0 = 0.0078125f; cv1 = 0.0078125f;
      } else {
        float b0 = dot4(u[0][0], cf[g][0][0]) + dot4(u[0][1], cf[g][0][1]);
        float b1 = dot4(u[1][0], cf[g][1][0]) + dot4(u[1][1], cf[g][1][1]);
        if (MODE == 2) { b0 += (float)bo[g][0]; b1 += (float)bo[g][1]; }
        if (MODE == 1) {
          f16x2 bw; bw[0] = (_Float16)b0; bw[1] = (_Float16)b1;
          *(f16x2*)(b_new + (size_t)(g0 + g) * 16384 + h * 128 + c0) = bw;
        }
        float m = fmaxf(b0, b1);
#pragma unroll
        for (int off = 32; off > 0; off >>= 1) m = fmaxf(m, __shfl_xor(m, off));
        const float e0 = __expf(b0 - m), e1 = __expf(b1 - m);
        float s = e0 + e1;
#pragma unroll
        for (int off = 32; off > 0; off >>= 1) s += __shfl_xor(s, off);
        const float inv = 1.f / s;
        cv0 = e0 * inv; cv1 = e1 * inv;
      }
      av[g][0][0] += cv0 * u[0][0]; av[g][0][1] += cv0 * u[0][1];
      av[g][1][0] += cv1 * u[1][0]; av[g][1][1] += cv1 * u[1][1];
    }
  }
#pragma unroll
  for (int g = 0; g < 4; ++g)
#pragma unroll
    for (int cc = 0; cc < 2; ++cc) {
      *(f32x4*)&vacc[wv][g][c0 + cc][0] = av[g][cc][0];
      *(f32x4*)&vacc[wv][g][c0 + cc][4] = av[g][cc][1];
    }
  __syncthreads();

  const float al = alpha[0];
  const int rg = tid >> 6;
  const int rc = (tid & 63) * 2;
#pragma unroll
  for (int cc = 0; cc < 2; ++cc) {
    const int c = rc + cc;
    f32x4 s0 = *(const f32x4*)&vacc[0][rg][c][0];
    f32x4 s1 = *(const f32x4*)&vacc[0][rg][c][4];
#pragma unroll
    for (int wq = 1; wq < 4; ++wq) {
      s0 += *(const f32x4*)&vacc[wq][rg][c][0];
      s1 += *(const f32x4*)&vacc[wq][rg][c][4];
    }
    s0 *= al; s1 *= al;
    *(f32x4*)(v_buf + (size_t)(g0 + rg) * 1024 + c * 8) = s0;
    *(f32x4*)(v_buf + (size_t)(g0 + rg) * 1024 + c * 8 + 4) = s1;
    const float ss = dot4(s0, s0) + dot4(s1, s1);
    vn_buf[(g0 + rg) * 128 + c] = sqrtf(ss) * w_scale[c] + bias_vec[c];
  }
}

// ---------------- flash: p-partials = softmax-stream(vn @ Ebf^T) @ Ebf ----------------
__global__ __launch_bounds__(256, 2) void flash_kernel(
    const float* __restrict__ vn, const unsigned short* __restrict__ Ebf,
    float* __restrict__ o_part, float* __restrict__ ms_part)
{
  __shared__ short e_nat[64][136];
  __shared__ short e_tr[128][72];
  __shared__ short p_lds[4][16][72];
  const int xc = blockIdx.x;
  const int tid = threadIdx.x;
  const int w = tid >> 6, lane = tid & 63, lrow = lane & 15, lk8 = lane >> 4;
  const int rowbase = blockIdx.y * 64 + w * 16;

  bf16x8 qf[4];
#pragma unroll
  for (int kt = 0; kt < 4; ++kt) {
    const float* p = vn + (size_t)(rowbase + lrow) * 128 + kt * 32 + lk8 * 8;
    qf[kt] = pack8v(*(const f32x4*)p, *(const f32x4*)(p + 4));
  }

  f32x4 o_acc[8] = {{0,0,0,0},{0,0,0,0},{0,0,0,0},{0,0,0,0},
                    {0,0,0,0},{0,0,0,0},{0,0,0,0},{0,0,0,0}};
  float m_run[4] = {-1e30f, -1e30f, -1e30f, -1e30f};
  float s_run[4] = {0.f, 0.f, 0.f, 0.f};

  const int kbeg = xc * 1024;
  const int nst = (kbeg + 1024 <= 50048) ? 16 : (50048 - kbeg) / 64;
  const int sr = tid >> 2, sseg = (tid & 3) * 32;

  for (int st = 0; st < nst; ++st) {
    const int v0 = kbeg + st * 64;
    {
      bf16x8 ev[4];
#pragma unroll
      for (int q = 0; q < 4; ++q)
        ev[q] = *(const bf16x8*)(Ebf + (size_t)(v0 + sr) * 128 + sseg + q * 8);
#pragma unroll
      for (int q = 0; q < 4; ++q)
        *(bf16x8*)&e_nat[sr][sseg + q * 8] = ev[q];
#pragma unroll
      for (int q = 0; q < 4; ++q)
#pragma unroll
        for (int j = 0; j < 8; ++j)
          e_tr[sseg + q * 8 + j][sr] = ev[q][j];
    }
    __syncthreads();
    f32x4 sacc[4] = {{0,0,0,0},{0,0,0,0},{0,0,0,0},{0,0,0,0}};
#pragma unroll
    for (int kt = 0; kt < 4; ++kt) {
#pragma unroll
      for (int nt = 0; nt < 4; ++nt) {
        const bf16x8 bfr = *(const bf16x8*)&e_nat[nt * 16 + lrow][kt * 32 + lk8 * 8];
        sacc[nt] = mfma16(qf[kt], bfr, sacc[nt]);
      }
    }
    if (v0 + 64 > 50001) {
#pragma unroll
      for (int nt = 0; nt < 4; ++nt)
        if (v0 + nt * 16 + lrow >= 50001)
          sacc[nt] = (f32x4){-1e30f, -1e30f, -1e30f, -1e30f};
    }
#pragma unroll
    for (int e2 = 0; e2 < 4; ++e2) {
      float mt = fmaxf(fmaxf(sacc[0][e2], sacc[1][e2]), fmaxf(sacc[2][e2], sacc[3][e2]));
      mt = fmaxf(mt, __shfl_xor(mt, 1));
      mt = fmaxf(mt, __shfl_xor(mt, 2));
      mt = fmaxf(mt, __shfl_xor(mt, 4));
      mt = fmaxf(mt, __shfl_xor(mt, 8));
      const float mn = fmaxf(m_run[e2], mt);
      const float scale = __expf(m_run[e2] - mn);
      m_run[e2] = mn;
      float pv[4];
#pragma unroll
      for (int nt = 0; nt < 4; ++nt) pv[nt] = __expf(sacc[nt][e2] - mn);
      float ps = pv[0] + pv[1] + pv[2] + pv[3];
      ps += __shfl_xor(ps, 1);
      ps += __shfl_xor(ps, 2);
      ps += __shfl_xor(ps, 4);
      ps += __shfl_xor(ps, 8);
      s_run[e2] = s_run[e2] * scale + ps;
#pragma unroll
      for (int nt8 = 0; nt8 < 8; ++nt8) o_acc[nt8][e2] *= scale;
#pragma unroll
      for (int nt = 0; nt < 4; ++nt)
        p_lds[w][lk8 * 4 + e2][nt * 16 + lrow] = f2bf(pv[nt]);
    }
#pragma unroll
    for (int kt2 = 0; kt2 < 2; ++kt2) {
      const bf16x8 pa = *(const bf16x8*)&p_lds[w][lrow][kt2 * 32 + lk8 * 8];
#pragma unroll
      for (int nt8 = 0; nt8 < 8; ++nt8) {
        const bf16x8 bfr = *(const bf16x8*)&e_tr[nt8 * 16 + lrow][kt2 * 32 + lk8 * 8];
        o_acc[nt8] = mfma16(pa, bfr, o_acc[nt8]);
      }
    }
    __syncthreads();
  }

#pragma unroll
  for (int nt8 = 0; nt8 < 8; ++nt8)
#pragma unroll
    for (int e2 = 0; e2 < 4; ++e2)
      o_part[((size_t)xc * 512 + rowbase + lk8 * 4 + e2) * 128 + nt8 * 16 + lrow] = o_acc[nt8][e2];
  if (lrow == 0) {
#pragma unroll
    for (int e2 = 0; e2 < 4; ++e2) {
      const int row = rowbase + lk8 * 4 + e2;
      ms_part[((size_t)row * 49 + xc) * 2]     = m_run[e2];
      ms_part[((size_t)row * 49 + xc) * 2 + 1] = s_run[e2];
    }
  }
}

// ---------------- combine partials -> p, then coef = concat(p, v) @ W_coef ----------------
__global__ __launch_bounds__(256) void combine_coef_kernel(
    const float* __restrict__ o_part, const float* __restrict__ ms_part,
    const float* __restrict__ v_buf, const float* __restrict__ W_coef,
    float* __restrict__ coef_buf)
{
  __shared__ float wg[4][64];
  __shared__ float p_s[4][128];
  const int g0 = blockIdx.x * 4;
  const int tid = threadIdx.x;
  const int w = tid >> 6, lane = tid & 63;
  {
    const int row = g0 + w;
    float ml = -1e30f, sl = 0.f;
    if (lane < 49) {
      ml = ms_part[((size_t)row * 49 + lane) * 2];
      sl = ms_part[((size_t)row * 49 + lane) * 2 + 1];
    }
    float M = ml;
#pragma unroll
    for (int off = 32; off > 0; off >>= 1) M = fmaxf(M, __shfl_xor(M, off));
    float e = (lane < 49) ? sl * __expf(ml - M) : 0.f;
    float S = e;
#pragma unroll
    for (int off = 32; off > 0; off >>= 1) S += __shfl_xor(S, off);
    const float inv = 1.f / S;
    if (lane < 49) wg[w][lane] = __expf(ml - M) * inv;
  }
  __syncthreads();
  {
    const int d = tid & 127, gh = tid >> 7;
    for (int gg = gh; gg < 4; gg += 2) {
      const int row = g0 + gg;
      float acc = 0.f;
      for (int x = 0; x < 49; ++x)
        acc += o_part[((size_t)x * 512 + row) * 128 + d] * wg[gg][x];
      p_s[gg][d] = acc;
    }
  }
  __syncthreads();
  const int c = tid >> 1, dh = (tid & 1) * 4;
  float vg[4][8];
#pragma unroll
  for (int g = 0; g < 4; ++g) {
    const f32x4 va = *(const f32x4*)(v_buf + (size_t)(g0 + g) * 1024 + c * 8);
    const f32x4 vb = *(const f32x4*)(v_buf + (size_t)(g0 + g) * 1024 + c * 8 + 4);
    vg[g][0]=va[0]; vg[g][1]=va[1]; vg[g][2]=va[2]; vg[g][3]=va[3];
    vg[g][4]=vb[0]; vg[g][5]=vb[1]; vg[g][6]=vb[2]; vg[g][7]=vb[3];
  }
  const float* wc = W_coef + (size_t)c * 1088 + dh;
  f32x4 acc4[4] = {{0,0,0,0},{0,0,0,0},{0,0,0,0},{0,0,0,0}};
  for (int dp = 0; dp < 128; ++dp) {
    const f32x4 w4 = *(const f32x4*)(wc + (size_t)dp * 8);
#pragma unroll
    for (int g = 0; g < 4; ++g) acc4[g] += p_s[g][dp] * w4;
  }
#pragma unroll
  for (int q = 0; q < 8; ++q) {
    const f32x4 w4 = *(const f32x4*)(wc + (size_t)(128 + q) * 8);
#pragma unroll
    for (int g = 0; g < 4; ++g) acc4[g] += vg[g][q] * w4;
  }
#pragma unroll
  for (int g = 0; g < 4; ++g)
    *(f32x4*)(coef_buf + (size_t)(g0 + g) * 1024 + c * 8 + dh) = acc4[g];
}

// ---------------- final logits fp32 into d_out (stages from fp32 item_emb) ----------------
__global__ __launch_bounds__(512) void logits32_kernel(
    const float* __restrict__ vn, const float* __restrict__ E,
    float* __restrict__ out)
{
  __shared__ short et[64][136];
  const int n0 = blockIdx.x * 64;
  const int tid = threadIdx.x;
  const int wave = tid >> 6, lane = tid & 63, lrow = lane & 15, lk8 = lane >> 4;
  {
    const int r = tid >> 3, ks = (tid & 7) * 16;
    const int v = n0 + r;
    f32x4 a = {0,0,0,0}, b = {0,0,0,0}, c = {0,0,0,0}, d = {0,0,0,0};
    if (v < 50001) {
      const float* p = E + (size_t)v * 128 + ks;
      a = *(const f32x4*)p; b = *(const f32x4*)(p + 4);
      c = *(const f32x4*)(p + 8); d = *(const f32x4*)(p + 12);
    }
    *(bf16x8*)&et[r][ks] = pack8v(a, b);
    *(bf16x8*)&et[r][ks + 8] = pack8v(c, d);
  }
  __syncthreads();
  for (int mb = 0; mb < 4; ++mb) {
    const int m0 = mb * 128;
    const int arow = m0 + wave * 16 + lrow;
    bf16x8 afr[4];
#pragma unroll
    for (int kt = 0; kt < 4; ++kt) {
      const float* p = vn + (size_t)arow * 128 + kt * 32 + lk8 * 8;
      afr[kt] = pack8v(*(const f32x4*)p, *(const f32x4*)(p + 4));
    }
    f32x4 acc[4] = {{0,0,0,0},{0,0,0,0},{0,0,0,0},{0,0,0,0}};
#pragma unroll
    for (int kt = 0; kt < 4; ++kt) {
#pragma unroll
      for (int nt = 0; nt < 4; ++nt) {
        const bf16x8 bfr = *(const bf16x8*)&et[nt * 16 + lrow][kt * 32 + lk8 * 8];
        acc[nt] = mfma16(afr[kt], bfr, acc[nt]);
      }
    }
#pragma unroll
    for (int nt = 0; nt < 4; ++nt) {
      const int col = n0 + nt * 16 + lrow;
      if (col < 50001) {
        const int row = m0 + wave * 16 + lk8 * 4;
#pragma unroll
        for (int e2 = 0; e2 < 4; ++e2)
          out[(size_t)(row + e2) * 50001 + col] = acc[nt][e2];
      }
    }
  }
}

extern "C" void kernel_launch(void* const* d_in, const int* in_sizes, int n_in,
                              void* d_out, int out_size, void* d_ws, size_t ws_size,
                              hipStream_t stream) {
  const int* seq0 = (const int*)d_in[0];
  const int* seq1 = (const int*)d_in[1];
  const int* seq2 = (const int*)d_in[2];
  const int* seq3 = (const int*)d_in[3];
  const float* item_emb = (const float*)d_in[4];
  const float* Wih = (const float*)d_in[5];
  const float* Whh = (const float*)d_in[6];
  const float* bih = (const float*)d_in[7];
  const float* bhh = (const float*)d_in[8];
  const float* W = (const float*)d_in[9];
  const float* w_scale = (const float*)d_in[10];
  const float* bias_vec = (const float*)d_in[11];
  const float* alpha = (const float*)d_in[12];
  const float* W_coef = (const float*)d_in[13];
  float* out = (float*)d_out;

  char* ws = (char*)d_ws;
  float* e_buf       = (float*)(ws);               // 1 MB
  _Float16* b_state  = (_Float16*)(ws + 1048576);  // 16.7 MB (fp16)
  float* v_buf    = (float*)(ws + 34603008);       // 2 MB
  float* vn_buf   = (float*)(ws + 36700160);       // 256 KB
  float* coef_buf = (float*)(ws + 37224448);       // 2 MB
  float* o_part   = (float*)(ws + 39325696);       // 12.85 MB
  float* ms_part  = (float*)(ws + 52170752);       // 200 KB

  unsigned short* gi_t50   = (unsigned short*)(ws + 1048576);  // 57.6 MB overlay
  unsigned short* gi_click = (unsigned short*)d_out;           // 76.8 MB in d_out
  unsigned short* Ebf = (unsigned short*)((char*)d_out + 78643200);  // 12.8 MB tail

  gi_gemm_kernel<<<dim3(700), 512, 0, stream>>>(seq0, seq1, seq2, seq3, item_emb, Wih,
                                                gi_t50, gi_click);
  gru_rec7_kernel<<<dim3(384), 256, 0, stream>>>(Whh, bih, bhh, gi_t50, gi_click,
                                                 item_emb, Ebf, e_buf);
  // iter 0: c uniform
  route_kernel<0><<<dim3(128), 256, 0, stream>>>(nullptr, nullptr, e_buf, W, nullptr,
                                                 w_scale, bias_vec, alpha, v_buf, vn_buf);
  flash_kernel<<<dim3(49, 8), 256, 0, stream>>>(vn_buf, Ebf, o_part, ms_part);
  combine_coef_kernel<<<dim3(128), 256, 0, stream>>>(o_part, ms_part, v_buf, W_coef, coef_buf);
  // iter 1: b1 = delta(coef0); v1
  route_kernel<1><<<dim3(128), 256, 0, stream>>>(nullptr, b_state, e_buf, W, coef_buf,
                                                 w_scale, bias_vec, alpha, v_buf, vn_buf);
  flash_kernel<<<dim3(49, 8), 256, 0, stream>>>(vn_buf, Ebf, o_part, ms_part);
  combine_coef_kernel<<<dim3(128), 256, 0, stream>>>(o_part, ms_part, v_buf, W_coef, coef_buf);
  // iter 2 (final): b2 = b1 + delta(coef1); v2
  route_kernel<2><<<dim3(128), 256, 0, stream>>>(b_state, nullptr, e_buf, W, coef_buf,
                                                 w_scale, bias_vec, alpha, v_buf, vn_buf);
  logits32_kernel<<<dim3(782), 512, 0, stream>>>(vn_buf, item_emb, out);
}

// Round 15
// 645.250 us; speedup vs baseline: 1.3824x; 1.2368x over previous
//
#include <hip/hip_runtime.h>
#include <math.h>

typedef __attribute__((ext_vector_type(8))) short bf16x8;
typedef __attribute__((ext_vector_type(4))) float f32x4;
typedef __attribute__((ext_vector_type(2))) float f32x2;
typedef __attribute__((ext_vector_type(4))) unsigned short u16x4;
typedef __attribute__((ext_vector_type(2))) _Float16 f16x2;

static __device__ __forceinline__ short f2bf(float f) {
  unsigned u = __builtin_bit_cast(unsigned, f);
  u += 0x7fffu + ((u >> 16) & 1u);
  return (short)(u >> 16);
}
static __device__ __forceinline__ float bf2f(unsigned short s) {
  unsigned u = ((unsigned)s) << 16;
  return __builtin_bit_cast(float, u);
}
static __device__ __forceinline__ f32x4 mfma16(bf16x8 a, bf16x8 b, f32x4 c) {
  return __builtin_amdgcn_mfma_f32_16x16x32_bf16(a, b, c, 0, 0, 0);
}
static __device__ __forceinline__ bf16x8 pack8v(f32x4 a, f32x4 b) {
  bf16x8 r;
  r[0]=f2bf(a[0]); r[1]=f2bf(a[1]); r[2]=f2bf(a[2]); r[3]=f2bf(a[3]);
  r[4]=f2bf(b[0]); r[5]=f2bf(b[1]); r[6]=f2bf(b[2]); r[7]=f2bf(b[3]);
  return r;
}
static __device__ __forceinline__ float fastrcp(float x) {
  float r;
  asm("v_rcp_f32_e32 %0, %1" : "=v"(r) : "v"(x));
  return r;
}
static __device__ __forceinline__ float dot4(f32x4 a, f32x4 b) {
  return a[0]*b[0] + a[1]*b[1] + a[2]*b[2] + a[3]*b[3];
}

#define LGKM_BARRIER() do {                                   \
    asm volatile("s_waitcnt lgkmcnt(0)" ::: "memory");        \
    __builtin_amdgcn_s_barrier();                             \
    __builtin_amdgcn_sched_barrier(0);                        \
  } while (0)

// ---------------- gi = x @ Wih^T, quad tiles; prefetch-pipelined gather ----------------
__global__ __launch_bounds__(512) void gi_gemm_kernel(
    const int* __restrict__ seq0, const int* __restrict__ seq1,
    const int* __restrict__ seq2, const int* __restrict__ seq3,
    const float* __restrict__ item_emb, const float* __restrict__ Wih,
    unsigned short* __restrict__ gi_t50, unsigned short* __restrict__ gi_click)
{
  const int b = blockIdx.x;
  int beh, tile0;
  if (b < 100)      { beh = 0; tile0 = b * 16; }
  else if (b < 200) { beh = 1; tile0 = (b - 100) * 16; }
  else if (b < 300) { beh = 2; tile0 = (b - 200) * 16; }
  else              { beh = 3; tile0 = (b - 300) * 16; }
  const int T = (beh == 3) ? 200 : 50;
  const int* seq = (beh == 0) ? seq0 : (beh == 1) ? seq1 : (beh == 2) ? seq2 : seq3;
  unsigned short* gibase = (beh == 3) ? gi_click : (gi_t50 + (size_t)beh * 9830400);

  const int tid = threadIdx.x;
  const int wave = tid >> 6, lane = tid & 63, lrow = lane & 15, lk8 = lane >> 4;
  const int bcol = wave * 16 + lrow;

  bf16x8 wif[3][4];
  const float* WihB = Wih + (size_t)beh * 384 * 128;
#pragma unroll
  for (int g = 0; g < 3; ++g) {
    const int wr = g * 128 + bcol;
#pragma unroll
    for (int kt = 0; kt < 4; ++kt) {
      const int k0 = kt * 32 + lk8 * 8;
      f32x4 a0 = *(const f32x4*)(WihB + (size_t)wr * 128 + k0);
      f32x4 a1 = *(const f32x4*)(WihB + (size_t)wr * 128 + k0 + 4);
      wif[g][kt] = pack8v(a0, a1);
    }
  }

  __shared__ short xt[16][132];
  const int gj = tid >> 5;
  const int gc = (tid & 31) * 4;

#define SEQ_ADDR(TI, OUT) do {                                    \
    const int _tile = tile0 + (TI);                               \
    const int _r0 = _tile / T;                                    \
    const int _t = _tile - _r0 * T;                               \
    OUT = seq[(size_t)(_r0 * 16 + gj) * T + _t];                  \
  } while (0)

  int sidx_cur, sidx_nxt = 0;
  SEQ_ADDR(0, sidx_cur);
  f32x4 xv_cur = *(const f32x4*)(item_emb + (size_t)sidx_cur * 128 + gc);
  SEQ_ADDR(1, sidx_nxt);

  for (int ti = 0; ti < 16; ++ti) {
    xt[gj][gc]     = f2bf(xv_cur[0]);
    xt[gj][gc + 1] = f2bf(xv_cur[1]);
    xt[gj][gc + 2] = f2bf(xv_cur[2]);
    xt[gj][gc + 3] = f2bf(xv_cur[3]);
    __syncthreads();
    // prefetch next tile's x (and the sidx after) while computing this tile
    f32x4 xv_nxt = {0.f, 0.f, 0.f, 0.f};
    int sidx_n2 = 0;
    if (ti + 1 < 16)
      xv_nxt = *(const f32x4*)(item_emb + (size_t)sidx_nxt * 128 + gc);
    if (ti + 2 < 16) SEQ_ADDR(ti + 2, sidx_n2);

    bf16x8 ax[4];
#pragma unroll
    for (int kt = 0; kt < 4; ++kt)
      ax[kt] = *(const bf16x8*)&xt[lrow][kt * 32 + lk8 * 8];
    f32x4 acc[3] = {{0,0,0,0},{0,0,0,0},{0,0,0,0}};
#pragma unroll
    for (int kt = 0; kt < 4; ++kt) {
      acc[0] = mfma16(ax[kt], wif[0][kt], acc[0]);
      acc[1] = mfma16(ax[kt], wif[1][kt], acc[1]);
      acc[2] = mfma16(ax[kt], wif[2][kt], acc[2]);
    }
    {
      const int tile = tile0 + ti;
      const int r0blk = tile / T;
      const int t = tile - r0blk * T;
      unsigned short* base = gibase + ((size_t)(r0blk * 4 + lk8) * T + t) * 1536;
      unsigned short* dst = base + bcol * 4;
#pragma unroll
      for (int g = 0; g < 3; ++g) {
        u16x4 o;
        o[0] = (unsigned short)f2bf(acc[g][0]);
        o[1] = (unsigned short)f2bf(acc[g][1]);
        o[2] = (unsigned short)f2bf(acc[g][2]);
        o[3] = (unsigned short)f2bf(acc[g][3]);
        *(u16x4*)(dst + g * 512) = o;
      }
    }
    __syncthreads();
    xv_cur = xv_nxt;
    sidx_nxt = sidx_n2;
  }
#undef SEQ_ADDR
}

// ---------------- GRU recurrence (blocks 0..511) + Ebf-cast workers (512..639) ----------------
__global__ __launch_bounds__(256, 2) void gru_rec5w_kernel(
    const float* __restrict__ Whh, const float* __restrict__ bih,
    const float* __restrict__ bhh,
    const unsigned short* __restrict__ gi_t50,
    const unsigned short* __restrict__ gi_click,
    const float* __restrict__ item_emb, unsigned short* __restrict__ Ebf,
    float* __restrict__ e_out)
{
  __shared__ short h0[16][140];
  __shared__ short h1[16][140];
  const int tid = threadIdx.x;

  if (blockIdx.x >= 512) {
    const int wb = blockIdx.x - 512;
    for (size_t i8 = (size_t)(wb * 256 + tid) * 8; i8 < 50048u * 128u; i8 += 32768u * 8u) {
      const int row = (int)(i8 >> 7);
      bf16x8 o = {0,0,0,0,0,0,0,0};
      if (row < 50001) {
        const f32x4 a = *(const f32x4*)(item_emb + i8);
        const f32x4 b = *(const f32x4*)(item_emb + i8 + 4);
        o = pack8v(a, b);
      }
      *(bf16x8*)(Ebf + i8) = o;
    }
    return;
  }

  const int beh = blockIdx.x >> 7;
  const int qt = blockIdx.x & 127;
  const int T = (beh == 3) ? 200 : 50;
  const unsigned short* gib =
      ((beh == 3) ? gi_click : (gi_t50 + (size_t)beh * 9830400)) + (size_t)qt * T * 1536;

  const int w = tid >> 6;
  const int lane = tid & 63;
  const int lrow = lane & 15;
  const int lk8 = lane >> 4;
  const int col0 = w * 32 + lrow;
  const int col1 = col0 + 16;

  bf16x8 whf[3][2][4];
  const float* WhhB = Whh + (size_t)beh * 384 * 128;
#pragma unroll
  for (int g = 0; g < 3; ++g) {
#pragma unroll
    for (int ct = 0; ct < 2; ++ct) {
      const int wr = g * 128 + (ct ? col1 : col0);
#pragma unroll
      for (int kt = 0; kt < 4; ++kt) {
        const int k0 = kt * 32 + lk8 * 8;
        f32x4 b0 = *(const f32x4*)(WhhB + (size_t)wr * 128 + k0);
        f32x4 b1 = *(const f32x4*)(WhhB + (size_t)wr * 128 + k0 + 4);
        whf[g][ct][kt] = pack8v(b0, b1);
      }
    }
  }
  float bR[2], bZ[2], bN[2], bHN[2];
#pragma unroll
  for (int ct = 0; ct < 2; ++ct) {
    const int c = ct ? col1 : col0;
    bR[ct]  = bih[beh * 384 + c] + bhh[beh * 384 + c];
    bZ[ct]  = bih[beh * 384 + 128 + c] + bhh[beh * 384 + 128 + c];
    bN[ct]  = bih[beh * 384 + 256 + c];
    bHN[ct] = bhh[beh * 384 + 256 + c];
  }

  for (int i = tid; i < 16 * 140; i += 256) { ((short*)h0)[i] = 0; ((short*)h1)[i] = 0; }
  float hreg[2] = {0.f, 0.f};
  __syncthreads();

  const unsigned short* gp0 = gib + col0 * 4 + lk8;
  const unsigned short* gp1 = gib + col1 * 4 + lk8;

  unsigned short ga[30], gb[30];

#define LOAD_CHUNK(BUF, C0) do {                                              \
    _Pragma("unroll")                                                         \
    for (int _s = 0; _s < 5; ++_s) {                                          \
      const size_t _o = (size_t)((C0) + _s) * 1536;                           \
      _Pragma("unroll")                                                       \
      for (int _g = 0; _g < 3; ++_g) {                                        \
        BUF[_s * 6 + 0 * 3 + _g] = gp0[_o + _g * 512];                        \
        BUF[_s * 6 + 1 * 3 + _g] = gp1[_o + _g * 512];                        \
      }                                                                       \
    }                                                                         \
  } while (0)

  short (*hin)[140] = h0;
  short (*hout)[140] = h1;

#define STEP(BUF, S) do {                                                     \
    bf16x8 ah[4];                                                             \
    _Pragma("unroll")                                                         \
    for (int kt = 0; kt < 4; ++kt)                                            \
      ah[kt] = *(const bf16x8*)&hin[lrow][kt * 32 + lk8 * 8];                 \
    f32x4 hr_[2], hz_[2], hn_[2];                                             \
    _Pragma("unroll")                                                         \
    for (int ct = 0; ct < 2; ++ct) {                                          \
      hr_[ct] = (f32x4){0,0,0,0}; hz_[ct] = (f32x4){0,0,0,0}; hn_[ct] = (f32x4){0,0,0,0}; \
      _Pragma("unroll")                                                       \
      for (int kt = 0; kt < 4; ++kt) {                                        \
        hr_[ct] = mfma16(ah[kt], whf[0][ct][kt], hr_[ct]);                    \
        hz_[ct] = mfma16(ah[kt], whf[1][ct][kt], hz_[ct]);                    \
        hn_[ct] = mfma16(ah[kt], whf[2][ct][kt], hn_[ct]);                    \
      }                                                                       \
    }                                                                         \
    _Pragma("unroll")                                                         \
    for (int ct = 0; ct < 2; ++ct) {                                          \
      const float xr = bf2f(BUF[(S)*6 + ct*3 + 0]) + bR[ct] + hr_[ct][0];     \
      const float xz = bf2f(BUF[(S)*6 + ct*3 + 1]) + bZ[ct] + hz_[ct][0];     \
      const float ea = __expf(-xr);                                           \
      const float eb = __expf(-xz);                                           \
      const float pa = 1.f + ea, pb = 1.f + eb;                               \
      const float rd = fastrcp(pa * pb);                                      \
      const float rr = pb * rd;                                               \
      const float zz = pa * rd;                                               \
      const float tn = bf2f(BUF[(S)*6 + ct*3 + 2]) + bN[ct] + rr * (hn_[ct][0] + bHN[ct]); \
      const float tt = __expf(-2.f * tn);                                     \
      const float nn = (1.f - tt) * fastrcp(1.f + tt);                        \
      hreg[ct] = nn + zz * (hreg[ct] - nn);                                   \
      hout[lk8 * 4][ct ? col1 : col0] = f2bf(hreg[ct]);                       \
    }                                                                         \
    LGKM_BARRIER();                                                           \
    short (*_tmp)[140] = hin; hin = hout; hout = _tmp;                        \
  } while (0)

  LOAD_CHUNK(ga, 0);
  for (int c = 0; c < T; c += 10) {
    if (c + 5 < T) LOAD_CHUNK(gb, c + 5);
    STEP(ga, 0); STEP(ga, 1); STEP(ga, 2); STEP(ga, 3); STEP(ga, 4);
    if (c + 10 < T) LOAD_CHUNK(ga, c + 10);
    STEP(gb, 0); STEP(gb, 1); STEP(gb, 2); STEP(gb, 3); STEP(gb, 4);
  }
#undef STEP
#undef LOAD_CHUNK

#pragma unroll
  for (int ct = 0; ct < 2; ++ct)
    e_out[(size_t)(qt * 4 + lk8) * 512 + (ct ? col1 : col0) * 4 + beh] = hreg[ct];
}

// ---------------- route: fused [combine p + coef] + b-update + softmax(c) + v + vn ----------------
// MODE 0: cv uniform (no coef). MODE 1: coef from partials, b=delta, write b. MODE 2: b=b_old+delta.
template<int MODE>
__global__ __launch_bounds__(256, 1) void route_kernel(
    const _Float16* __restrict__ b_old, _Float16* __restrict__ b_new,
    const float* __restrict__ e_buf, const float* __restrict__ W,
    const float* __restrict__ o_part, const float* __restrict__ ms_part,
    const float* __restrict__ W_coef,
    const float* __restrict__ w_scale, const float* __restrict__ bias_vec,
    const float* __restrict__ alpha,
    float* __restrict__ v_buf, float* __restrict__ vn_buf)
{
  __shared__ float e_lds[4][128][4];
  __shared__ float vacc[4][4][128][8];
  __shared__ float cf_lds[4][128][8];
  __shared__ float wg[4][64];
  __shared__ float p_s[4][128];
  const int g0 = blockIdx.x * 4;
  const int tid = threadIdx.x;
  const int wv = tid >> 6, ln = tid & 63;
  const int c0 = ln * 2;
  for (int i = tid; i < 2048; i += 256) ((float*)e_lds)[i] = e_buf[(size_t)g0 * 512 + i];

  if (MODE != 0) {
    // phase A1: per-row merge weights from (m,s) partials
    {
      const int row = g0 + wv;
      float ml = -1e30f, sl = 0.f;
      if (ln < 49) {
        ml = ms_part[((size_t)row * 49 + ln) * 2];
        sl = ms_part[((size_t)row * 49 + ln) * 2 + 1];
      }
      float M = ml;
#pragma unroll
      for (int off = 32; off > 0; off >>= 1) M = fmaxf(M, __shfl_xor(M, off));
      float e = (ln < 49) ? sl * __expf(ml - M) : 0.f;
      float S = e;
#pragma unroll
      for (int off = 32; off > 0; off >>= 1) S += __shfl_xor(S, off);
      const float inv = 1.f / S;
      if (ln < 49) wg[wv][ln] = __expf(ml - M) * inv;
    }
    __syncthreads();
    // phase A2: p rows (weighted partial merge)
    {
      const int d = tid & 127, gh = tid >> 7;
      for (int gg = gh; gg < 4; gg += 2) {
        const int row = g0 + gg;
        float acc = 0.f;
        for (int x = 0; x < 49; ++x)
          acc += o_part[((size_t)x * 512 + row) * 128 + d] * wg[gg][x];
        p_s[gg][d] = acc;
      }
    }
    __syncthreads();
    // phase A3: coef = concat(p, v_prev) @ W_coef -> cf_lds
    {
      const int c = tid >> 1, dh = (tid & 1) * 4;
      float vg[4][8];
#pragma unroll
      for (int g = 0; g < 4; ++g) {
        const f32x4 va = *(const f32x4*)(v_buf + (size_t)(g0 + g) * 1024 + c * 8);
        const f32x4 vb = *(const f32x4*)(v_buf + (size_t)(g0 + g) * 1024 + c * 8 + 4);
        vg[g][0]=va[0]; vg[g][1]=va[1]; vg[g][2]=va[2]; vg[g][3]=va[3];
        vg[g][4]=vb[0]; vg[g][5]=vb[1]; vg[g][6]=vb[2]; vg[g][7]=vb[3];
      }
      const float* wc = W_coef + (size_t)c * 1088 + dh;
      f32x4 acc4[4] = {{0,0,0,0},{0,0,0,0},{0,0,0,0},{0,0,0,0}};
      for (int dp = 0; dp < 128; ++dp) {
        const f32x4 w4 = *(const f32x4*)(wc + (size_t)dp * 8);
#pragma unroll
        for (int g = 0; g < 4; ++g) acc4[g] += p_s[g][dp] * w4;
      }
#pragma unroll
      for (int q = 0; q < 8; ++q) {
        const f32x4 w4 = *(const f32x4*)(wc + (size_t)(128 + q) * 8);
#pragma unroll
        for (int g = 0; g < 4; ++g) acc4[g] += vg[g][q] * w4;
      }
#pragma unroll
      for (int g = 0; g < 4; ++g)
        *(f32x4*)&cf_lds[g][c][dh] = acc4[g];
    }
  }
  __syncthreads();

  f32x4 cf[4][2][2];
  if (MODE != 0) {
#pragma unroll
    for (int g = 0; g < 4; ++g)
#pragma unroll
      for (int cc = 0; cc < 2; ++cc) {
        cf[g][cc][0] = *(const f32x4*)&cf_lds[g][c0 + cc][0];
        cf[g][cc][1] = *(const f32x4*)&cf_lds[g][c0 + cc][4];
      }
  }

  f32x4 av[4][2][2];
#pragma unroll
  for (int g = 0; g < 4; ++g)
#pragma unroll
    for (int cc = 0; cc < 2; ++cc) { av[g][cc][0] = (f32x4){0,0,0,0}; av[g][cc][1] = (f32x4){0,0,0,0}; }

  const int hbeg = wv * 32;
  for (int h = hbeg; h < hbeg + 32; ++h) {
    f32x4 wr[4][2][2];
#pragma unroll
    for (int t = 0; t < 4; ++t) {
      const float* wp = W + ((size_t)(h * 4 + t) * 128 + c0) * 8;
      wr[t][0][0] = *(const f32x4*)(wp);
      wr[t][0][1] = *(const f32x4*)(wp + 4);
      wr[t][1][0] = *(const f32x4*)(wp + 8);
      wr[t][1][1] = *(const f32x4*)(wp + 12);
    }
    f16x2 bo[4];
    if (MODE == 2) {
#pragma unroll
      for (int g = 0; g < 4; ++g)
        bo[g] = *(const f16x2*)(b_old + (size_t)(g0 + g) * 16384 + h * 128 + c0);
    }
#pragma unroll
    for (int g = 0; g < 4; ++g) {
      const f32x4 ev = *(const f32x4*)&e_lds[g][h][0];
      f32x4 u[2][2];
#pragma unroll
      for (int cc = 0; cc < 2; ++cc)
#pragma unroll
        for (int dd = 0; dd < 2; ++dd)
          u[cc][dd] = ev[0]*wr[0][cc][dd] + ev[1]*wr[1][cc][dd]
                    + ev[2]*wr[2][cc][dd] + ev[3]*wr[3][cc][dd];
      float cv0, cv1;
      if (MODE == 0) {
        cv0 = 0.0078125f; cv1 = 0.0078125f;
      } else {
        float b0 = dot4(u[0][0], cf[g][0][0]) + dot4(u[0][1], cf[g][0][1]);
        float b1 = dot4(u[1][0], cf[g][1][0]) + dot4(u[1][1], cf[g][1][1]);
        if (MODE == 2) { b0 += (float)bo[g][0]; b1 += (float)bo[g][1]; }
        if (MODE == 1) {
          f16x2 bw; bw[0] = (_Float16)b0; bw[1] = (_Float16)b1;
          *(f16x2*)(b_new + (size_t)(g0 + g) * 16384 + h * 128 + c0) = bw;
        }
        float m = fmaxf(b0, b1);
#pragma unroll
        for (int off = 32; off > 0; off >>= 1) m = fmaxf(m, __shfl_xor(m, off));
        const float e0 = __expf(b0 - m), e1 = __expf(b1 - m);
        float s = e0 + e1;
#pragma unroll
        for (int off = 32; off > 0; off >>= 1) s += __shfl_xor(s, off);
        const float inv = 1.f / s;
        cv0 = e0 * inv; cv1 = e1 * inv;
      }
      av[g][0][0] += cv0 * u[0][0]; av[g][0][1] += cv0 * u[0][1];
      av[g][1][0] += cv1 * u[1][0]; av[g][1][1] += cv1 * u[1][1];
    }
  }
#pragma unroll
  for (int g = 0; g < 4; ++g)
#pragma unroll
    for (int cc = 0; cc < 2; ++cc) {
      *(f32x4*)&vacc[wv][g][c0 + cc][0] = av[g][cc][0];
      *(f32x4*)&vacc[wv][g][c0 + cc][4] = av[g][cc][1];
    }
  __syncthreads();

  const float al = alpha[0];
  const int rg = tid >> 6;
  const int rc = (tid & 63) * 2;
#pragma unroll
  for (int cc = 0; cc < 2; ++cc) {
    const int c = rc + cc;
    f32x4 s0 = *(const f32x4*)&vacc[0][rg][c][0];
    f32x4 s1 = *(const f32x4*)&vacc[0][rg][c][4];
#pragma unroll
    for (int wq = 1; wq < 4; ++wq) {
      s0 += *(const f32x4*)&vacc[wq][rg][c][0];
      s1 += *(const f32x4*)&vacc[wq][rg][c][4];
    }
    s0 *= al; s1 *= al;
    *(f32x4*)(v_buf + (size_t)(g0 + rg) * 1024 + c * 8) = s0;
    *(f32x4*)(v_buf + (size_t)(g0 + rg) * 1024 + c * 8 + 4) = s1;
    const float ss = dot4(s0, s0) + dot4(s1, s1);
    vn_buf[(g0 + rg) * 128 + c] = sqrtf(ss) * w_scale[c] + bias_vec[c];
  }
}

// ---------------- flash: p-partials = softmax-stream(vn @ Ebf^T) @ Ebf ----------------
__global__ __launch_bounds__(256, 2) void flash_kernel(
    const float* __restrict__ vn, const unsigned short* __restrict__ Ebf,
    float* __restrict__ o_part, float* __restrict__ ms_part)
{
  __shared__ short e_nat[64][136];
  __shared__ short e_tr[128][72];
  __shared__ short p_lds[4][16][72];
  const int xc = blockIdx.x;
  const int tid = threadIdx.x;
  const int w = tid >> 6, lane = tid & 63, lrow = lane & 15, lk8 = lane >> 4;
  const int rowbase = blockIdx.y * 64 + w * 16;

  bf16x8 qf[4];
#pragma unroll
  for (int kt = 0; kt < 4; ++kt) {
    const float* p = vn + (size_t)(rowbase + lrow) * 128 + kt * 32 + lk8 * 8;
    qf[kt] = pack8v(*(const f32x4*)p, *(const f32x4*)(p + 4));
  }

  f32x4 o_acc[8] = {{0,0,0,0},{0,0,0,0},{0,0,0,0},{0,0,0,0},
                    {0,0,0,0},{0,0,0,0},{0,0,0,0},{0,0,0,0}};
  float m_run[4] = {-1e30f, -1e30f, -1e30f, -1e30f};
  float s_run[4] = {0.f, 0.f, 0.f, 0.f};

  const int kbeg = xc * 1024;
  const int nst = (kbeg + 1024 <= 50048) ? 16 : (50048 - kbeg) / 64;
  const int sr = tid >> 2, sseg = (tid & 3) * 32;

  for (int st = 0; st < nst; ++st) {
    const int v0 = kbeg + st * 64;
    {
      bf16x8 ev[4];
#pragma unroll
      for (int q = 0; q < 4; ++q)
        ev[q] = *(const bf16x8*)(Ebf + (size_t)(v0 + sr) * 128 + sseg + q * 8);
#pragma unroll
      for (int q = 0; q < 4; ++q)
        *(bf16x8*)&e_nat[sr][sseg + q * 8] = ev[q];
#pragma unroll
      for (int q = 0; q < 4; ++q)
#pragma unroll
        for (int j = 0; j < 8; ++j)
          e_tr[sseg + q * 8 + j][sr] = ev[q][j];
    }
    __syncthreads();
    f32x4 sacc[4] = {{0,0,0,0},{0,0,0,0},{0,0,0,0},{0,0,0,0}};
#pragma unroll
    for (int kt = 0; kt < 4; ++kt) {
#pragma unroll
      for (int nt = 0; nt < 4; ++nt) {
        const bf16x8 bfr = *(const bf16x8*)&e_nat[nt * 16 + lrow][kt * 32 + lk8 * 8];
        sacc[nt] = mfma16(qf[kt], bfr, sacc[nt]);
      }
    }
    if (v0 + 64 > 50001) {
#pragma unroll
      for (int nt = 0; nt < 4; ++nt)
        if (v0 + nt * 16 + lrow >= 50001)
          sacc[nt] = (f32x4){-1e30f, -1e30f, -1e30f, -1e30f};
    }
#pragma unroll
    for (int e2 = 0; e2 < 4; ++e2) {
      float mt = fmaxf(fmaxf(sacc[0][e2], sacc[1][e2]), fmaxf(sacc[2][e2], sacc[3][e2]));
      mt = fmaxf(mt, __shfl_xor(mt, 1));
      mt = fmaxf(mt, __shfl_xor(mt, 2));
      mt = fmaxf(mt, __shfl_xor(mt, 4));
      mt = fmaxf(mt, __shfl_xor(mt, 8));
      const float mn = fmaxf(m_run[e2], mt);
      const float scale = __expf(m_run[e2] - mn);
      m_run[e2] = mn;
      float pv[4];
#pragma unroll
      for (int nt = 0; nt < 4; ++nt) pv[nt] = __expf(sacc[nt][e2] - mn);
      float ps = pv[0] + pv[1] + pv[2] + pv[3];
      ps += __shfl_xor(ps, 1);
      ps += __shfl_xor(ps, 2);
      ps += __shfl_xor(ps, 4);
      ps += __shfl_xor(ps, 8);
      s_run[e2] = s_run[e2] * scale + ps;
#pragma unroll
      for (int nt8 = 0; nt8 < 8; ++nt8) o_acc[nt8][e2] *= scale;
#pragma unroll
      for (int nt = 0; nt < 4; ++nt)
        p_lds[w][lk8 * 4 + e2][nt * 16 + lrow] = f2bf(pv[nt]);
    }
#pragma unroll
    for (int kt2 = 0; kt2 < 2; ++kt2) {
      const bf16x8 pa = *(const bf16x8*)&p_lds[w][lrow][kt2 * 32 + lk8 * 8];
#pragma unroll
      for (int nt8 = 0; nt8 < 8; ++nt8) {
        const bf16x8 bfr = *(const bf16x8*)&e_tr[nt8 * 16 + lrow][kt2 * 32 + lk8 * 8];
        o_acc[nt8] = mfma16(pa, bfr, o_acc[nt8]);
      }
    }
    __syncthreads();
  }

#pragma unroll
  for (int nt8 = 0; nt8 < 8; ++nt8)
#pragma unroll
    for (int e2 = 0; e2 < 4; ++e2)
      o_part[((size_t)xc * 512 + rowbase + lk8 * 4 + e2) * 128 + nt8 * 16 + lrow] = o_acc[nt8][e2];
  if (lrow == 0) {
#pragma unroll
    for (int e2 = 0; e2 < 4; ++e2) {
      const int row = rowbase + lk8 * 4 + e2;
      ms_part[((size_t)row * 49 + xc) * 2]     = m_run[e2];
      ms_part[((size_t)row * 49 + xc) * 2 + 1] = s_run[e2];
    }
  }
}

// ---------------- final logits fp32 into d_out (stages from fp32 item_emb) ----------------
__global__ __launch_bounds__(512) void logits32_kernel(
    const float* __restrict__ vn, const float* __restrict__ E,
    float* __restrict__ out)
{
  __shared__ short et[64][136];
  const int n0 = blockIdx.x * 64;
  const int tid = threadIdx.x;
  const int wave = tid >> 6, lane = tid & 63, lrow = lane & 15, lk8 = lane >> 4;
  {
    const int r = tid >> 3, ks = (tid & 7) * 16;
    const int v = n0 + r;
    f32x4 a = {0,0,0,0}, b = {0,0,0,0}, c = {0,0,0,0}, d = {0,0,0,0};
    if (v < 50001) {
      const float* p = E + (size_t)v * 128 + ks;
      a = *(const f32x4*)p; b = *(const f32x4*)(p + 4);
      c = *(const f32x4*)(p + 8); d = *(const f32x4*)(p + 12);
    }
    *(bf16x8*)&et[r][ks] = pack8v(a, b);
    *(bf16x8*)&et[r][ks + 8] = pack8v(c, d);
  }
  __syncthreads();
  for (int mb = 0; mb < 4; ++mb) {
    const int m0 = mb * 128;
    const int arow = m0 + wave * 16 + lrow;
    bf16x8 afr[4];
#pragma unroll
    for (int kt = 0; kt < 4; ++kt) {
      const float* p = vn + (size_t)arow * 128 + kt * 32 + lk8 * 8;
      afr[kt] = pack8v(*(const f32x4*)p, *(const f32x4*)(p + 4));
    }
    f32x4 acc[4] = {{0,0,0,0},{0,0,0,0},{0,0,0,0},{0,0,0,0}};
#pragma unroll
    for (int kt = 0; kt < 4; ++kt) {
#pragma unroll
      for (int nt = 0; nt < 4; ++nt) {
        const bf16x8 bfr = *(const bf16x8*)&et[nt * 16 + lrow][kt * 32 + lk8 * 8];
        acc[nt] = mfma16(afr[kt], bfr, acc[nt]);
      }
    }
#pragma unroll
    for (int nt = 0; nt < 4; ++nt) {
      const int col = n0 + nt * 16 + lrow;
      if (col < 50001) {
        const int row = m0 + wave * 16 + lk8 * 4;
#pragma unroll
        for (int e2 = 0; e2 < 4; ++e2)
          out[(size_t)(row + e2) * 50001 + col] = acc[nt][e2];
      }
    }
  }
}

extern "C" void kernel_launch(void* const* d_in, const int* in_sizes, int n_in,
                              void* d_out, int out_size, void* d_ws, size_t ws_size,
                              hipStream_t stream) {
  const int* seq0 = (const int*)d_in[0];
  const int* seq1 = (const int*)d_in[1];
  const int* seq2 = (const int*)d_in[2];
  const int* seq3 = (const int*)d_in[3];
  const float* item_emb = (const float*)d_in[4];
  const float* Wih = (const float*)d_in[5];
  const float* Whh = (const float*)d_in[6];
  const float* bih = (const float*)d_in[7];
  const float* bhh = (const float*)d_in[8];
  const float* W = (const float*)d_in[9];
  const float* w_scale = (const float*)d_in[10];
  const float* bias_vec = (const float*)d_in[11];
  const float* alpha = (const float*)d_in[12];
  const float* W_coef = (const float*)d_in[13];
  float* out = (float*)d_out;

  char* ws = (char*)d_ws;
  float* e_buf       = (float*)(ws);               // 1 MB
  _Float16* b_state  = (_Float16*)(ws + 1048576);  // 16.7 MB (fp16)
  float* v_buf    = (float*)(ws + 34603008);       // 2 MB
  float* vn_buf   = (float*)(ws + 36700160);       // 256 KB
  float* o_part   = (float*)(ws + 39325696);       // 12.85 MB
  float* ms_part  = (float*)(ws + 52170752);       // 200 KB

  unsigned short* gi_t50   = (unsigned short*)(ws + 1048576);  // 57.6 MB overlay
  unsigned short* gi_click = (unsigned short*)d_out;           // 76.8 MB in d_out
  unsigned short* Ebf = (unsigned short*)((char*)d_out + 78643200);  // 12.8 MB tail

  gi_gemm_kernel<<<dim3(700), 512, 0, stream>>>(seq0, seq1, seq2, seq3, item_emb, Wih,
                                                gi_t50, gi_click);
  gru_rec5w_kernel<<<dim3(640), 256, 0, stream>>>(Whh, bih, bhh, gi_t50, gi_click,
                                                  item_emb, Ebf, e_buf);
  // iter 0: c uniform
  route_kernel<0><<<dim3(128), 256, 0, stream>>>(nullptr, nullptr, e_buf, W,
                                                 nullptr, nullptr, W_coef,
                                                 w_scale, bias_vec, alpha, v_buf, vn_buf);
  flash_kernel<<<dim3(49, 8), 256, 0, stream>>>(vn_buf, Ebf, o_part, ms_part);
  // iter 1: coef0 from partials + v0, b1 = delta(coef0), v1
  route_kernel<1><<<dim3(128), 256, 0, stream>>>(nullptr, b_state, e_buf, W,
                                                 o_part, ms_part, W_coef,
                                                 w_scale, bias_vec, alpha, v_buf, vn_buf);
  flash_kernel<<<dim3(49, 8), 256, 0, stream>>>(vn_buf, Ebf, o_part, ms_part);
  // iter 2 (final): coef1 from partials + v1, b2 = b1 + delta(coef1), v2
  route_kernel<2><<<dim3(128), 256, 0, stream>>>(b_state, nullptr, e_buf, W,
                                                 o_part, ms_part, W_coef,
                                                 w_scale, bias_vec, alpha, v_buf, vn_buf);
  logits32_kernel<<<dim3(782), 512, 0, stream>>>(vn_buf, item_emb, out);
}

// Round 16
// 643.898 us; speedup vs baseline: 1.3853x; 1.0021x over previous
//
#include <hip/hip_runtime.h>
#include <math.h>

typedef __attribute__((ext_vector_type(8))) short bf16x8;
typedef __attribute__((ext_vector_type(4))) float f32x4;
typedef __attribute__((ext_vector_type(2))) float f32x2;
typedef __attribute__((ext_vector_type(4))) unsigned short u16x4;
typedef __attribute__((ext_vector_type(2))) _Float16 f16x2;

static __device__ __forceinline__ short f2bf(float f) {
  unsigned u = __builtin_bit_cast(unsigned, f);
  u += 0x7fffu + ((u >> 16) & 1u);
  return (short)(u >> 16);
}
static __device__ __forceinline__ float bf2f(unsigned short s) {
  unsigned u = ((unsigned)s) << 16;
  return __builtin_bit_cast(float, u);
}
static __device__ __forceinline__ f32x4 mfma16(bf16x8 a, bf16x8 b, f32x4 c) {
  return __builtin_amdgcn_mfma_f32_16x16x32_bf16(a, b, c, 0, 0, 0);
}
static __device__ __forceinline__ bf16x8 pack8v(f32x4 a, f32x4 b) {
  bf16x8 r;
  r[0]=f2bf(a[0]); r[1]=f2bf(a[1]); r[2]=f2bf(a[2]); r[3]=f2bf(a[3]);
  r[4]=f2bf(b[0]); r[5]=f2bf(b[1]); r[6]=f2bf(b[2]); r[7]=f2bf(b[3]);
  return r;
}
static __device__ __forceinline__ float fastrcp(float x) {
  float r;
  asm("v_rcp_f32_e32 %0, %1" : "=v"(r) : "v"(x));
  return r;
}
static __device__ __forceinline__ float dot4(f32x4 a, f32x4 b) {
  return a[0]*b[0] + a[1]*b[1] + a[2]*b[2] + a[3]*b[3];
}

#define LGKM_BARRIER() do {                                   \
    asm volatile("s_waitcnt lgkmcnt(0)" ::: "memory");        \
    __builtin_amdgcn_s_barrier();                             \
    __builtin_amdgcn_sched_barrier(0);                        \
  } while (0)

// ---------------- gi = x @ Wih^T, quad tiles; prefetch-pipelined gather ----------------
__global__ __launch_bounds__(512) void gi_gemm_kernel(
    const int* __restrict__ seq0, const int* __restrict__ seq1,
    const int* __restrict__ seq2, const int* __restrict__ seq3,
    const float* __restrict__ item_emb, const float* __restrict__ Wih,
    unsigned short* __restrict__ gi_t50, unsigned short* __restrict__ gi_click)
{
  const int b = blockIdx.x;
  int beh, tile0;
  if (b < 100)      { beh = 0; tile0 = b * 16; }
  else if (b < 200) { beh = 1; tile0 = (b - 100) * 16; }
  else if (b < 300) { beh = 2; tile0 = (b - 200) * 16; }
  else              { beh = 3; tile0 = (b - 300) * 16; }
  const int T = (beh == 3) ? 200 : 50;
  const int* seq = (beh == 0) ? seq0 : (beh == 1) ? seq1 : (beh == 2) ? seq2 : seq3;
  unsigned short* gibase = (beh == 3) ? gi_click : (gi_t50 + (size_t)beh * 9830400);

  const int tid = threadIdx.x;
  const int wave = tid >> 6, lane = tid & 63, lrow = lane & 15, lk8 = lane >> 4;
  const int bcol = wave * 16 + lrow;

  bf16x8 wif[3][4];
  const float* WihB = Wih + (size_t)beh * 384 * 128;
#pragma unroll
  for (int g = 0; g < 3; ++g) {
    const int wr = g * 128 + bcol;
#pragma unroll
    for (int kt = 0; kt < 4; ++kt) {
      const int k0 = kt * 32 + lk8 * 8;
      f32x4 a0 = *(const f32x4*)(WihB + (size_t)wr * 128 + k0);
      f32x4 a1 = *(const f32x4*)(WihB + (size_t)wr * 128 + k0 + 4);
      wif[g][kt] = pack8v(a0, a1);
    }
  }

  __shared__ short xt[16][132];
  const int gj = tid >> 5;
  const int gc = (tid & 31) * 4;

#define SEQ_ADDR(TI, OUT) do {                                    \
    const int _tile = tile0 + (TI);                               \
    const int _r0 = _tile / T;                                    \
    const int _t = _tile - _r0 * T;                               \
    OUT = seq[(size_t)(_r0 * 16 + gj) * T + _t];                  \
  } while (0)

  int sidx_cur, sidx_nxt = 0;
  SEQ_ADDR(0, sidx_cur);
  f32x4 xv_cur = *(const f32x4*)(item_emb + (size_t)sidx_cur * 128 + gc);
  SEQ_ADDR(1, sidx_nxt);

  for (int ti = 0; ti < 16; ++ti) {
    xt[gj][gc]     = f2bf(xv_cur[0]);
    xt[gj][gc + 1] = f2bf(xv_cur[1]);
    xt[gj][gc + 2] = f2bf(xv_cur[2]);
    xt[gj][gc + 3] = f2bf(xv_cur[3]);
    __syncthreads();
    // prefetch next tile's x (and the sidx after) while computing this tile
    f32x4 xv_nxt = {0.f, 0.f, 0.f, 0.f};
    int sidx_n2 = 0;
    if (ti + 1 < 16)
      xv_nxt = *(const f32x4*)(item_emb + (size_t)sidx_nxt * 128 + gc);
    if (ti + 2 < 16) SEQ_ADDR(ti + 2, sidx_n2);

    bf16x8 ax[4];
#pragma unroll
    for (int kt = 0; kt < 4; ++kt)
      ax[kt] = *(const bf16x8*)&xt[lrow][kt * 32 + lk8 * 8];
    f32x4 acc[3] = {{0,0,0,0},{0,0,0,0},{0,0,0,0}};
#pragma unroll
    for (int kt = 0; kt < 4; ++kt) {
      acc[0] = mfma16(ax[kt], wif[0][kt], acc[0]);
      acc[1] = mfma16(ax[kt], wif[1][kt], acc[1]);
      acc[2] = mfma16(ax[kt], wif[2][kt], acc[2]);
    }
    {
      const int tile = tile0 + ti;
      const int r0blk = tile / T;
      const int t = tile - r0blk * T;
      unsigned short* base = gibase + ((size_t)(r0blk * 4 + lk8) * T + t) * 1536;
      unsigned short* dst = base + bcol * 4;
#pragma unroll
      for (int g = 0; g < 3; ++g) {
        u16x4 o;
        o[0] = (unsigned short)f2bf(acc[g][0]);
        o[1] = (unsigned short)f2bf(acc[g][1]);
        o[2] = (unsigned short)f2bf(acc[g][2]);
        o[3] = (unsigned short)f2bf(acc[g][3]);
        *(u16x4*)(dst + g * 512) = o;
      }
    }
    __syncthreads();
    xv_cur = xv_nxt;
    sidx_nxt = sidx_n2;
  }
#undef SEQ_ADDR
}

// ---------------- GRU recurrence (blocks 0..511) + Ebf-cast workers (512..639) ----------------
__global__ __launch_bounds__(256, 2) void gru_rec5w_kernel(
    const float* __restrict__ Whh, const float* __restrict__ bih,
    const float* __restrict__ bhh,
    const unsigned short* __restrict__ gi_t50,
    const unsigned short* __restrict__ gi_click,
    const float* __restrict__ item_emb, unsigned short* __restrict__ Ebf,
    float* __restrict__ e_out)
{
  __shared__ short h0[16][140];
  __shared__ short h1[16][140];
  const int tid = threadIdx.x;

  if (blockIdx.x >= 512) {
    const int wb = blockIdx.x - 512;
    for (size_t i8 = (size_t)(wb * 256 + tid) * 8; i8 < 50048u * 128u; i8 += 32768u * 8u) {
      const int row = (int)(i8 >> 7);
      bf16x8 o = {0,0,0,0,0,0,0,0};
      if (row < 50001) {
        const f32x4 a = *(const f32x4*)(item_emb + i8);
        const f32x4 b = *(const f32x4*)(item_emb + i8 + 4);
        o = pack8v(a, b);
      }
      *(bf16x8*)(Ebf + i8) = o;
    }
    return;
  }

  const int beh = blockIdx.x >> 7;
  const int qt = blockIdx.x & 127;
  const int T = (beh == 3) ? 200 : 50;
  const unsigned short* gib =
      ((beh == 3) ? gi_click : (gi_t50 + (size_t)beh * 9830400)) + (size_t)qt * T * 1536;

  const int w = tid >> 6;
  const int lane = tid & 63;
  const int lrow = lane & 15;
  const int lk8 = lane >> 4;
  const int col0 = w * 32 + lrow;
  const int col1 = col0 + 16;

  bf16x8 whf[3][2][4];
  const float* WhhB = Whh + (size_t)beh * 384 * 128;
#pragma unroll
  for (int g = 0; g < 3; ++g) {
#pragma unroll
    for (int ct = 0; ct < 2; ++ct) {
      const int wr = g * 128 + (ct ? col1 : col0);
#pragma unroll
      for (int kt = 0; kt < 4; ++kt) {
        const int k0 = kt * 32 + lk8 * 8;
        f32x4 b0 = *(const f32x4*)(WhhB + (size_t)wr * 128 + k0);
        f32x4 b1 = *(const f32x4*)(WhhB + (size_t)wr * 128 + k0 + 4);
        whf[g][ct][kt] = pack8v(b0, b1);
      }
    }
  }
  float bR[2], bZ[2], bN[2], bHN[2];
#pragma unroll
  for (int ct = 0; ct < 2; ++ct) {
    const int c = ct ? col1 : col0;
    bR[ct]  = bih[beh * 384 + c] + bhh[beh * 384 + c];
    bZ[ct]  = bih[beh * 384 + 128 + c] + bhh[beh * 384 + 128 + c];
    bN[ct]  = bih[beh * 384 + 256 + c];
    bHN[ct] = bhh[beh * 384 + 256 + c];
  }

  for (int i = tid; i < 16 * 140; i += 256) { ((short*)h0)[i] = 0; ((short*)h1)[i] = 0; }
  float hreg[2] = {0.f, 0.f};
  __syncthreads();

  const unsigned short* gp0 = gib + col0 * 4 + lk8;
  const unsigned short* gp1 = gib + col1 * 4 + lk8;

  unsigned short ga[30], gb[30];

#define LOAD_CHUNK(BUF, C0) do {                                              \
    _Pragma("unroll")                                                         \
    for (int _s = 0; _s < 5; ++_s) {                                          \
      const size_t _o = (size_t)((C0) + _s) * 1536;                           \
      _Pragma("unroll")                                                       \
      for (int _g = 0; _g < 3; ++_g) {                                        \
        BUF[_s * 6 + 0 * 3 + _g] = gp0[_o + _g * 512];                        \
        BUF[_s * 6 + 1 * 3 + _g] = gp1[_o + _g * 512];                        \
      }                                                                       \
    }                                                                         \
  } while (0)

  short (*hin)[140] = h0;
  short (*hout)[140] = h1;

#define STEP(BUF, S) do {                                                     \
    bf16x8 ah[4];                                                             \
    _Pragma("unroll")                                                         \
    for (int kt = 0; kt < 4; ++kt)                                            \
      ah[kt] = *(const bf16x8*)&hin[lrow][kt * 32 + lk8 * 8];                 \
    f32x4 hr_[2], hz_[2], hn_[2];                                             \
    __builtin_amdgcn_s_setprio(1);                                            \
    _Pragma("unroll")                                                         \
    for (int ct = 0; ct < 2; ++ct) {                                          \
      hr_[ct] = (f32x4){0,0,0,0}; hz_[ct] = (f32x4){0,0,0,0}; hn_[ct] = (f32x4){0,0,0,0}; \
      _Pragma("unroll")                                                       \
      for (int kt = 0; kt < 4; ++kt) {                                        \
        hr_[ct] = mfma16(ah[kt], whf[0][ct][kt], hr_[ct]);                    \
        hz_[ct] = mfma16(ah[kt], whf[1][ct][kt], hz_[ct]);                    \
        hn_[ct] = mfma16(ah[kt], whf[2][ct][kt], hn_[ct]);                    \
      }                                                                       \
    }                                                                         \
    __builtin_amdgcn_s_setprio(0);                                            \
    _Pragma("unroll")                                                         \
    for (int ct = 0; ct < 2; ++ct) {                                          \
      const float xr = bf2f(BUF[(S)*6 + ct*3 + 0]) + bR[ct] + hr_[ct][0];     \
      const float xz = bf2f(BUF[(S)*6 + ct*3 + 1]) + bZ[ct] + hz_[ct][0];     \
      const float ea = __expf(-xr);                                           \
      const float eb = __expf(-xz);                                           \
      const float pa = 1.f + ea, pb = 1.f + eb;                               \
      const float rd = fastrcp(pa * pb);                                      \
      const float rr = pb * rd;                                               \
      const float zz = pa * rd;                                               \
      const float tn = bf2f(BUF[(S)*6 + ct*3 + 2]) + bN[ct] + rr * (hn_[ct][0] + bHN[ct]); \
      const float tt = __expf(-2.f * tn);                                     \
      const float nn = (1.f - tt) * fastrcp(1.f + tt);                        \
      hreg[ct] = nn + zz * (hreg[ct] - nn);                                   \
      hout[lk8 * 4][ct ? col1 : col0] = f2bf(hreg[ct]);                       \
    }                                                                         \
    LGKM_BARRIER();                                                           \
    short (*_tmp)[140] = hin; hin = hout; hout = _tmp;                        \
  } while (0)

  LOAD_CHUNK(ga, 0);
  for (int c = 0; c < T; c += 10) {
    if (c + 5 < T) LOAD_CHUNK(gb, c + 5);
    STEP(ga, 0); STEP(ga, 1); STEP(ga, 2); STEP(ga, 3); STEP(ga, 4);
    if (c + 10 < T) LOAD_CHUNK(ga, c + 10);
    STEP(gb, 0); STEP(gb, 1); STEP(gb, 2); STEP(gb, 3); STEP(gb, 4);
  }
#undef STEP
#undef LOAD_CHUNK

#pragma unroll
  for (int ct = 0; ct < 2; ++ct)
    e_out[(size_t)(qt * 4 + lk8) * 512 + (ct ? col1 : col0) * 4 + beh] = hreg[ct];
}

// ---------------- route: fused [combine p + coef] + b-update + softmax(c) + v + vn ----------------
template<int MODE>
__global__ __launch_bounds__(256, 1) void route_kernel(
    const _Float16* __restrict__ b_old, _Float16* __restrict__ b_new,
    const float* __restrict__ e_buf, const float* __restrict__ W,
    const float* __restrict__ o_part, const float* __restrict__ ms_part,
    const float* __restrict__ W_coef,
    const float* __restrict__ w_scale, const float* __restrict__ bias_vec,
    const float* __restrict__ alpha,
    float* __restrict__ v_buf, float* __restrict__ vn_buf)
{
  __shared__ float e_lds[4][128][4];
  __shared__ float vacc[4][4][128][8];
  __shared__ float cf_lds[4][128][8];
  __shared__ float wg[4][64];
  __shared__ float p_s[4][128];
  const int g0 = blockIdx.x * 4;
  const int tid = threadIdx.x;
  const int wv = tid >> 6, ln = tid & 63;
  const int c0 = ln * 2;
  for (int i = tid; i < 2048; i += 256) ((float*)e_lds)[i] = e_buf[(size_t)g0 * 512 + i];

  if (MODE != 0) {
    {
      const int row = g0 + wv;
      float ml = -1e30f, sl = 0.f;
      if (ln < 49) {
        ml = ms_part[((size_t)row * 49 + ln) * 2];
        sl = ms_part[((size_t)row * 49 + ln) * 2 + 1];
      }
      float M = ml;
#pragma unroll
      for (int off = 32; off > 0; off >>= 1) M = fmaxf(M, __shfl_xor(M, off));
      float e = (ln < 49) ? sl * __expf(ml - M) : 0.f;
      float S = e;
#pragma unroll
      for (int off = 32; off > 0; off >>= 1) S += __shfl_xor(S, off);
      const float inv = 1.f / S;
      if (ln < 49) wg[wv][ln] = __expf(ml - M) * inv;
    }
    __syncthreads();
    {
      const int d = tid & 127, gh = tid >> 7;
      for (int gg = gh; gg < 4; gg += 2) {
        const int row = g0 + gg;
        float acc = 0.f;
        for (int x = 0; x < 49; ++x)
          acc += o_part[((size_t)x * 512 + row) * 128 + d] * wg[gg][x];
        p_s[gg][d] = acc;
      }
    }
    __syncthreads();
    {
      const int c = tid >> 1, dh = (tid & 1) * 4;
      float vg[4][8];
#pragma unroll
      for (int g = 0; g < 4; ++g) {
        const f32x4 va = *(const f32x4*)(v_buf + (size_t)(g0 + g) * 1024 + c * 8);
        const f32x4 vb = *(const f32x4*)(v_buf + (size_t)(g0 + g) * 1024 + c * 8 + 4);
        vg[g][0]=va[0]; vg[g][1]=va[1]; vg[g][2]=va[2]; vg[g][3]=va[3];
        vg[g][4]=vb[0]; vg[g][5]=vb[1]; vg[g][6]=vb[2]; vg[g][7]=vb[3];
      }
      const float* wc = W_coef + (size_t)c * 1088 + dh;
      f32x4 acc4[4] = {{0,0,0,0},{0,0,0,0},{0,0,0,0},{0,0,0,0}};
      for (int dp = 0; dp < 128; ++dp) {
        const f32x4 w4 = *(const f32x4*)(wc + (size_t)dp * 8);
#pragma unroll
        for (int g = 0; g < 4; ++g) acc4[g] += p_s[g][dp] * w4;
      }
#pragma unroll
      for (int q = 0; q < 8; ++q) {
        const f32x4 w4 = *(const f32x4*)(wc + (size_t)(128 + q) * 8);
#pragma unroll
        for (int g = 0; g < 4; ++g) acc4[g] += vg[g][q] * w4;
      }
#pragma unroll
      for (int g = 0; g < 4; ++g)
        *(f32x4*)&cf_lds[g][c][dh] = acc4[g];
    }
  }
  __syncthreads();

  f32x4 cf[4][2][2];
  if (MODE != 0) {
#pragma unroll
    for (int g = 0; g < 4; ++g)
#pragma unroll
      for (int cc = 0; cc < 2; ++cc) {
        cf[g][cc][0] = *(const f32x4*)&cf_lds[g][c0 + cc][0];
        cf[g][cc][1] = *(const f32x4*)&cf_lds[g][c0 + cc][4];
      }
  }

  f32x4 av[4][2][2];
#pragma unroll
  for (int g = 0; g < 4; ++g)
#pragma unroll
    for (int cc = 0; cc < 2; ++cc) { av[g][cc][0] = (f32x4){0,0,0,0}; av[g][cc][1] = (f32x4){0,0,0,0}; }

  const int hbeg = wv * 32;
  for (int h = hbeg; h < hbeg + 32; ++h) {
    f32x4 wr[4][2][2];
#pragma unroll
    for (int t = 0; t < 4; ++t) {
      const float* wp = W + ((size_t)(h * 4 + t) * 128 + c0) * 8;
      wr[t][0][0] = *(const f32x4*)(wp);
      wr[t][0][1] = *(const f32x4*)(wp + 4);
      wr[t][1][0] = *(const f32x4*)(wp + 8);
      wr[t][1][1] = *(const f32x4*)(wp + 12);
    }
    f16x2 bo[4];
    if (MODE == 2) {
#pragma unroll
      for (int g = 0; g < 4; ++g)
        bo[g] = *(const f16x2*)(b_old + (size_t)(g0 + g) * 16384 + h * 128 + c0);
    }
#pragma unroll
    for (int g = 0; g < 4; ++g) {
      const f32x4 ev = *(const f32x4*)&e_lds[g][h][0];
      f32x4 u[2][2];
#pragma unroll
      for (int cc = 0; cc < 2; ++cc)
#pragma unroll
        for (int dd = 0; dd < 2; ++dd)
          u[cc][dd] = ev[0]*wr[0][cc][dd] + ev[1]*wr[1][cc][dd]
                    + ev[2]*wr[2][cc][dd] + ev[3]*wr[3][cc][dd];
      float cv0, cv1;
      if (MODE == 0) {
        cv0 = 0.0078125f; cv1 = 0.0078125f;
      } else {
        float b0 = dot4(u[0][0], cf[g][0][0]) + dot4(u[0][1], cf[g][0][1]);
        float b1 = dot4(u[1][0], cf[g][1][0]) + dot4(u[1][1], cf[g][1][1]);
        if (MODE == 2) { b0 += (float)bo[g][0]; b1 += (float)bo[g][1]; }
        if (MODE == 1) {
          f16x2 bw; bw[0] = (_Float16)b0; bw[1] = (_Float16)b1;
          *(f16x2*)(b_new + (size_t)(g0 + g) * 16384 + h * 128 + c0) = bw;
        }
        float m = fmaxf(b0, b1);
#pragma unroll
        for (int off = 32; off > 0; off >>= 1) m = fmaxf(m, __shfl_xor(m, off));
        const float e0 = __expf(b0 - m), e1 = __expf(b1 - m);
        float s = e0 + e1;
#pragma unroll
        for (int off = 32; off > 0; off >>= 1) s += __shfl_xor(s, off);
        const float inv = 1.f / s;
        cv0 = e0 * inv; cv1 = e1 * inv;
      }
      av[g][0][0] += cv0 * u[0][0]; av[g][0][1] += cv0 * u[0][1];
      av[g][1][0] += cv1 * u[1][0]; av[g][1][1] += cv1 * u[1][1];
    }
  }
#pragma unroll
  for (int g = 0; g < 4; ++g)
#pragma unroll
    for (int cc = 0; cc < 2; ++cc) {
      *(f32x4*)&vacc[wv][g][c0 + cc][0] = av[g][cc][0];
      *(f32x4*)&vacc[wv][g][c0 + cc][4] = av[g][cc][1];
    }
  __syncthreads();

  const float al = alpha[0];
  const int rg = tid >> 6;
  const int rc = (tid & 63) * 2;
#pragma unroll
  for (int cc = 0; cc < 2; ++cc) {
    const int c = rc + cc;
    f32x4 s0 = *(const f32x4*)&vacc[0][rg][c][0];
    f32x4 s1 = *(const f32x4*)&vacc[0][rg][c][4];
#pragma unroll
    for (int wq = 1; wq < 4; ++wq) {
      s0 += *(const f32x4*)&vacc[wq][rg][c][0];
      s1 += *(const f32x4*)&vacc[wq][rg][c][4];
    }
    s0 *= al; s1 *= al;
    *(f32x4*)(v_buf + (size_t)(g0 + rg) * 1024 + c * 8) = s0;
    *(f32x4*)(v_buf + (size_t)(g0 + rg) * 1024 + c * 8 + 4) = s1;
    const float ss = dot4(s0, s0) + dot4(s1, s1);
    vn_buf[(g0 + rg) * 128 + c] = sqrtf(ss) * w_scale[c] + bias_vec[c];
  }
}

// ---------------- flash: p-partials = softmax-stream(vn @ Ebf^T) @ Ebf ----------------
__global__ __launch_bounds__(256, 2) void flash_kernel(
    const float* __restrict__ vn, const unsigned short* __restrict__ Ebf,
    float* __restrict__ o_part, float* __restrict__ ms_part)
{
  __shared__ short e_nat[64][136];
  __shared__ short e_tr[128][72];
  __shared__ short p_lds[4][16][72];
  const int xc = blockIdx.x;
  const int tid = threadIdx.x;
  const int w = tid >> 6, lane = tid & 63, lrow = lane & 15, lk8 = lane >> 4;
  const int rowbase = blockIdx.y * 64 + w * 16;

  bf16x8 qf[4];
#pragma unroll
  for (int kt = 0; kt < 4; ++kt) {
    const float* p = vn + (size_t)(rowbase + lrow) * 128 + kt * 32 + lk8 * 8;
    qf[kt] = pack8v(*(const f32x4*)p, *(const f32x4*)(p + 4));
  }

  f32x4 o_acc[8] = {{0,0,0,0},{0,0,0,0},{0,0,0,0},{0,0,0,0},
                    {0,0,0,0},{0,0,0,0},{0,0,0,0},{0,0,0,0}};
  float m_run[4] = {-1e30f, -1e30f, -1e30f, -1e30f};
  float s_run[4] = {0.f, 0.f, 0.f, 0.f};

  const int kbeg = xc * 1024;
  const int nst = (kbeg + 1024 <= 50048) ? 16 : (50048 - kbeg) / 64;
  const int sr = tid >> 2, sseg = (tid & 3) * 32;

  for (int st = 0; st < nst; ++st) {
    const int v0 = kbeg + st * 64;
    {
      bf16x8 ev[4];
#pragma unroll
      for (int q = 0; q < 4; ++q)
        ev[q] = *(const bf16x8*)(Ebf + (size_t)(v0 + sr) * 128 + sseg + q * 8);
#pragma unroll
      for (int q = 0; q < 4; ++q)
        *(bf16x8*)&e_nat[sr][sseg + q * 8] = ev[q];
#pragma unroll
      for (int q = 0; q < 4; ++q)
#pragma unroll
        for (int j = 0; j < 8; ++j)
          e_tr[sseg + q * 8 + j][sr] = ev[q][j];
    }
    __syncthreads();
    f32x4 sacc[4] = {{0,0,0,0},{0,0,0,0},{0,0,0,0},{0,0,0,0}};
    __builtin_amdgcn_s_setprio(1);
#pragma unroll
    for (int kt = 0; kt < 4; ++kt) {
#pragma unroll
      for (int nt = 0; nt < 4; ++nt) {
        const bf16x8 bfr = *(const bf16x8*)&e_nat[nt * 16 + lrow][kt * 32 + lk8 * 8];
        sacc[nt] = mfma16(qf[kt], bfr, sacc[nt]);
      }
    }
    __builtin_amdgcn_s_setprio(0);
    if (v0 + 64 > 50001) {
#pragma unroll
      for (int nt = 0; nt < 4; ++nt)
        if (v0 + nt * 16 + lrow >= 50001)
          sacc[nt] = (f32x4){-1e30f, -1e30f, -1e30f, -1e30f};
    }
#pragma unroll
    for (int e2 = 0; e2 < 4; ++e2) {
      float mt = fmaxf(fmaxf(sacc[0][e2], sacc[1][e2]), fmaxf(sacc[2][e2], sacc[3][e2]));
      mt = fmaxf(mt, __shfl_xor(mt, 1));
      mt = fmaxf(mt, __shfl_xor(mt, 2));
      mt = fmaxf(mt, __shfl_xor(mt, 4));
      mt = fmaxf(mt, __shfl_xor(mt, 8));
      const float mn = fmaxf(m_run[e2], mt);
      const float scale = __expf(m_run[e2] - mn);
      m_run[e2] = mn;
      float pv[4];
#pragma unroll
      for (int nt = 0; nt < 4; ++nt) pv[nt] = __expf(sacc[nt][e2] - mn);
      float ps = pv[0] + pv[1] + pv[2] + pv[3];
      ps += __shfl_xor(ps, 1);
      ps += __shfl_xor(ps, 2);
      ps += __shfl_xor(ps, 4);
      ps += __shfl_xor(ps, 8);
      s_run[e2] = s_run[e2] * scale + ps;
#pragma unroll
      for (int nt8 = 0; nt8 < 8; ++nt8) o_acc[nt8][e2] *= scale;
#pragma unroll
      for (int nt = 0; nt < 4; ++nt)
        p_lds[w][lk8 * 4 + e2][nt * 16 + lrow] = f2bf(pv[nt]);
    }
    __builtin_amdgcn_s_setprio(1);
#pragma unroll
    for (int kt2 = 0; kt2 < 2; ++kt2) {
      const bf16x8 pa = *(const bf16x8*)&p_lds[w][lrow][kt2 * 32 + lk8 * 8];
#pragma unroll
      for (int nt8 = 0; nt8 < 8; ++nt8) {
        const bf16x8 bfr = *(const bf16x8*)&e_tr[nt8 * 16 + lrow][kt2 * 32 + lk8 * 8];
        o_acc[nt8] = mfma16(pa, bfr, o_acc[nt8]);
      }
    }
    __builtin_amdgcn_s_setprio(0);
    __syncthreads();
  }

#pragma unroll
  for (int nt8 = 0; nt8 < 8; ++nt8)
#pragma unroll
    for (int e2 = 0; e2 < 4; ++e2)
      o_part[((size_t)xc * 512 + rowbase + lk8 * 4 + e2) * 128 + nt8 * 16 + lrow] = o_acc[nt8][e2];
  if (lrow == 0) {
#pragma unroll
    for (int e2 = 0; e2 < 4; ++e2) {
      const int row = rowbase + lk8 * 4 + e2;
      ms_part[((size_t)row * 49 + xc) * 2]     = m_run[e2];
      ms_part[((size_t)row * 49 + xc) * 2 + 1] = s_run[e2];
    }
  }
}

// ---------------- final logits fp32 into d_out (stages from fp32 item_emb) ----------------
__global__ __launch_bounds__(512) void logits32_kernel(
    const float* __restrict__ vn, const float* __restrict__ E,
    float* __restrict__ out)
{
  __shared__ short et[64][136];
  const int n0 = blockIdx.x * 64;
  const int tid = threadIdx.x;
  const int wave = tid >> 6, lane = tid & 63, lrow = lane & 15, lk8 = lane >> 4;
  {
    const int r = tid >> 3, ks = (tid & 7) * 16;
    const int v = n0 + r;
    f32x4 a = {0,0,0,0}, b = {0,0,0,0}, c = {0,0,0,0}, d = {0,0,0,0};
    if (v < 50001) {
      const float* p = E + (size_t)v * 128 + ks;
      a = *(const f32x4*)p; b = *(const f32x4*)(p + 4);
      c = *(const f32x4*)(p + 8); d = *(const f32x4*)(p + 12);
    }
    *(bf16x8*)&et[r][ks] = pack8v(a, b);
    *(bf16x8*)&et[r][ks + 8] = pack8v(c, d);
  }
  __syncthreads();
  for (int mb = 0; mb < 4; ++mb) {
    const int m0 = mb * 128;
    const int arow = m0 + wave * 16 + lrow;
    bf16x8 afr[4];
#pragma unroll
    for (int kt = 0; kt < 4; ++kt) {
      const float* p = vn + (size_t)arow * 128 + kt * 32 + lk8 * 8;
      afr[kt] = pack8v(*(const f32x4*)p, *(const f32x4*)(p + 4));
    }
    f32x4 acc[4] = {{0,0,0,0},{0,0,0,0},{0,0,0,0},{0,0,0,0}};
#pragma unroll
    for (int kt = 0; kt < 4; ++kt) {
#pragma unroll
      for (int nt = 0; nt < 4; ++nt) {
        const bf16x8 bfr = *(const bf16x8*)&et[nt * 16 + lrow][kt * 32 + lk8 * 8];
        acc[nt] = mfma16(afr[kt], bfr, acc[nt]);
      }
    }
#pragma unroll
    for (int nt = 0; nt < 4; ++nt) {
      const int col = n0 + nt * 16 + lrow;
      if (col < 50001) {
        const int row = m0 + wave * 16 + lk8 * 4;
#pragma unroll
        for (int e2 = 0; e2 < 4; ++e2)
          out[(size_t)(row + e2) * 50001 + col] = acc[nt][e2];
      }
    }
  }
}

extern "C" void kernel_launch(void* const* d_in, const int* in_sizes, int n_in,
                              void* d_out, int out_size, void* d_ws, size_t ws_size,
                              hipStream_t stream) {
  const int* seq0 = (const int*)d_in[0];
  const int* seq1 = (const int*)d_in[1];
  const int* seq2 = (const int*)d_in[2];
  const int* seq3 = (const int*)d_in[3];
  const float* item_emb = (const float*)d_in[4];
  const float* Wih = (const float*)d_in[5];
  const float* Whh = (const float*)d_in[6];
  const float* bih = (const float*)d_in[7];
  const float* bhh = (const float*)d_in[8];
  const float* W = (const float*)d_in[9];
  const float* w_scale = (const float*)d_in[10];
  const float* bias_vec = (const float*)d_in[11];
  const float* alpha = (const float*)d_in[12];
  const float* W_coef = (const float*)d_in[13];
  float* out = (float*)d_out;

  char* ws = (char*)d_ws;
  float* e_buf       = (float*)(ws);               // 1 MB
  _Float16* b_state  = (_Float16*)(ws + 1048576);  // 16.7 MB (fp16)
  float* v_buf    = (float*)(ws + 34603008);       // 2 MB
  float* vn_buf   = (float*)(ws + 36700160);       // 256 KB
  float* o_part   = (float*)(ws + 39325696);       // 12.85 MB
  float* ms_part  = (float*)(ws + 52170752);       // 200 KB

  unsigned short* gi_t50   = (unsigned short*)(ws + 1048576);  // 57.6 MB overlay
  unsigned short* gi_click = (unsigned short*)d_out;           // 76.8 MB in d_out
  unsigned short* Ebf = (unsigned short*)((char*)d_out + 78643200);  // 12.8 MB tail

  gi_gemm_kernel<<<dim3(700), 512, 0, stream>>>(seq0, seq1, seq2, seq3, item_emb, Wih,
                                                gi_t50, gi_click);
  gru_rec5w_kernel<<<dim3(640), 256, 0, stream>>>(Whh, bih, bhh, gi_t50, gi_click,
                                                  item_emb, Ebf, e_buf);
  // iter 0: c uniform
  route_kernel<0><<<dim3(128), 256, 0, stream>>>(nullptr, nullptr, e_buf, W,
                                                 nullptr, nullptr, W_coef,
                                                 w_scale, bias_vec, alpha, v_buf, vn_buf);
  flash_kernel<<<dim3(49, 8), 256, 0, stream>>>(vn_buf, Ebf, o_part, ms_part);
  // iter 1: coef0 from partials + v0, b1 = delta(coef0), v1
  route_kernel<1><<<dim3(128), 256, 0, stream>>>(nullptr, b_state, e_buf, W,
                                                 o_part, ms_part, W_coef,
                                                 w_scale, bias_vec, alpha, v_buf, vn_buf);
  flash_kernel<<<dim3(49, 8), 256, 0, stream>>>(vn_buf, Ebf, o_part, ms_part);
  // iter 2 (final): coef1 from partials + v1, b2 = b1 + delta(coef1), v2
  route_kernel<2><<<dim3(128), 256, 0, stream>>>(b_state, nullptr, e_buf, W,
                                                 o_part, ms_part, W_coef,
                                                 w_scale, bias_vec, alpha, v_buf, vn_buf);
  logits32_kernel<<<dim3(782), 512, 0, stream>>>(vn_buf, item_emb, out);
}